// Round 1
// baseline (6884.968 us; speedup 1.0000x reference)
//
#include <hip/hip_runtime.h>
#include <math.h>

typedef unsigned short ushort;
typedef unsigned int uint;
typedef __attribute__((ext_vector_type(8))) short bf16x8;
typedef __attribute__((ext_vector_type(4))) float f32x4;

#define B_  32
#define S_  24
#define T_  24
#define E_  620
#define EP_ 640
#define H_  1000
#define HP_ 1024
#define V_  30000
#define M2_ 1000
#define KW_ 512

__device__ __forceinline__ ushort f2bf(float f) {
  uint u = __float_as_uint(f);
  u += 0x7FFFu + ((u >> 16) & 1u);
  return (ushort)(u >> 16);
}
__device__ __forceinline__ float bf2f(ushort s) {
  return __uint_as_float(((uint)s) << 16);
}

// ---------------------------------------------------------------------------
// weight conversion: fp32 [N][K] -> bf16 [N][Kp] zero-padded
// ---------------------------------------------------------------------------
struct ConvJobs {
  const float* in[19];
  ushort* out[19];
  int K[19], Kp[19];
};
__global__ __launch_bounds__(256) void conv_small(ConvJobs a) {
  int j = blockIdx.y, row = blockIdx.x;
  const float* ip = a.in[j] + (size_t)row * a.K[j];
  ushort* op = a.out[j] + (size_t)row * a.Kp[j];
  for (int k = threadIdx.x; k < a.Kp[j]; k += 256)
    op[k] = (k < a.K[j]) ? f2bf(ip[k]) : (ushort)0;
}

__global__ __launch_bounds__(256) void conv_wo(const float* __restrict__ in,
                                               ushort* __restrict__ out) {
  int row = blockIdx.x;
  const float* ip = in + (size_t)row * 500;
  ushort* op = out + (size_t)row * 512;
  int k = threadIdx.x;
  op[k] = (k < 500) ? f2bf(ip[k]) : (ushort)0;
  k += 256;
  op[k] = (k < 500) ? f2bf(ip[k]) : (ushort)0;
}

// ---------------------------------------------------------------------------
// embedding gather -> bf16, K padded 620->640
// ---------------------------------------------------------------------------
__global__ __launch_bounds__(256) void gather16(
    const int* __restrict__ src, const int* __restrict__ tgt,
    const float* __restrict__ semb, const float* __restrict__ temb,
    ushort* __restrict__ XE, ushort* __restrict__ YE) {
  int row = blockIdx.x;
  int isT = row >= S_ * B_;
  int r = isT ? row - S_ * B_ : row;
  int st = r >> 5, b = r & 31;
  int tok = isT ? tgt[b * T_ + st] : src[b * S_ + st];
  const float* e = (isT ? temb : semb) + (size_t)tok * E_;
  ushort* o = (isT ? YE : XE) + (size_t)r * EP_;
  for (int k = threadIdx.x; k < EP_; k += 256)
    o[k] = (k < E_) ? f2bf(e[k]) : (ushort)0;
}

// ---------------------------------------------------------------------------
// bf16 MFMA GEMM: C = A @ Bw^T. A [M][Kp] bf16, Bw [N][Kp] bf16.
// 128x128 tile, 4 waves, each 64x64 (4x4 frags of 16x16x32).
// Register-staged double buffer: prefetch tile k+1 into VGPRs during MFMA of
// tile k (2-phase pipeline, hides HBM latency of the 16..32-iter K loop).
// mode 0: fp32 store C[row][col] (ldc)
// mode 1: maxout: v = acc+e1[row][col]+e2[row&31][col]; pair-max -> bf16 tmax
// mode 2: scatter: row=t*32+b -> C[(b*T+t)*ldc + col]
// ---------------------------------------------------------------------------
struct MG {
  const ushort* A[8];
  const ushort* Bw[8];
  float* C[8];
  int M, N, Kp, ldc;
  int mode;
  const float* e1;
  const float* e2;
  ushort* tmax;
};

__global__ __launch_bounds__(256) void mgemm(MG g) {
  __shared__ ushort As[128 * 40];
  __shared__ ushort Bs[128 * 40];
  const int z = blockIdx.z;
  const ushort* __restrict__ A = g.A[z];
  const ushort* __restrict__ Bw = g.Bw[z];
  const int tid = threadIdx.x;
  const int wave = tid >> 6, lane = tid & 63;
  const int lm = lane & 15, kq = lane >> 4;
  const int wm = (wave >> 1) * 64, wn = (wave & 1) * 64;
  const int m0 = blockIdx.y * 128, n0 = blockIdx.x * 128;
  const int Kp = g.Kp;

  f32x4 acc[4][4];
#pragma unroll
  for (int i = 0; i < 4; ++i)
#pragma unroll
    for (int j = 0; j < 4; ++j) acc[i][j] = (f32x4){0.f, 0.f, 0.f, 0.f};

  const int row_s = tid >> 2, seg = tid & 3;

  uint4 va[2], vb[2];
  auto ld = [&](int k0) {
#pragma unroll
    for (int p = 0; p < 2; ++p) {
      int gm = m0 + row_s + p * 64;
      va[p] = make_uint4(0, 0, 0, 0);
      if (gm < g.M) va[p] = *(const uint4*)(A + (size_t)gm * Kp + k0 + seg * 8);
      int gn = n0 + row_s + p * 64;
      vb[p] = make_uint4(0, 0, 0, 0);
      if (gn < g.N) vb[p] = *(const uint4*)(Bw + (size_t)gn * Kp + k0 + seg * 8);
    }
  };

  ld(0);
  for (int k0 = 0; k0 < Kp; k0 += 32) {
#pragma unroll
    for (int p = 0; p < 2; ++p) {
      int row = row_s + p * 64;
      *(uint4*)&As[row * 40 + seg * 8] = va[p];
      *(uint4*)&Bs[row * 40 + seg * 8] = vb[p];
    }
    __syncthreads();
    if (k0 + 32 < Kp) ld(k0 + 32);  // issue next-tile loads under the MFMAs
    bf16x8 af[4], bfr[4];
#pragma unroll
    for (int i = 0; i < 4; ++i)
      af[i] = *(const bf16x8*)&As[(wm + i * 16 + lm) * 40 + kq * 8];
#pragma unroll
    for (int j = 0; j < 4; ++j)
      bfr[j] = *(const bf16x8*)&Bs[(wn + j * 16 + lm) * 40 + kq * 8];
#pragma unroll
    for (int i = 0; i < 4; ++i)
#pragma unroll
      for (int j = 0; j < 4; ++j)
        acc[i][j] = __builtin_amdgcn_mfma_f32_16x16x32_bf16(af[i], bfr[j], acc[i][j], 0, 0, 0);
    __syncthreads();
  }

#pragma unroll
  for (int i = 0; i < 4; ++i) {
    int grow = m0 + wm + i * 16 + kq * 4;
#pragma unroll
    for (int j = 0; j < 4; ++j) {
      int gcol = n0 + wn + j * 16 + lm;
#pragma unroll
      for (int r = 0; r < 4; ++r) {
        int row = grow + r;
        float v = acc[i][j][r];
        if (g.mode == 0) {
          if (row < g.M && gcol < g.N) g.C[z][(size_t)row * g.ldc + gcol] = v;
        } else if (g.mode == 1) {
          float vv = v;
          if (row < g.M && gcol < g.N)
            vv += g.e1[(size_t)row * M2_ + gcol] + g.e2[(size_t)(row & 31) * M2_ + gcol];
          float other = __shfl_xor(vv, 1);
          if ((lane & 1) == 0 && row < g.M && gcol < g.N)
            g.tmax[(size_t)row * KW_ + (gcol >> 1)] = f2bf(fmaxf(vv, other));
        } else {
          if (row < g.M && gcol < g.N) {
            int t = row >> 5, b = row & 31;
            g.C[z][((size_t)b * T_ + t) * (size_t)g.ldc + gcol] = v;
          }
        }
      }
    }
  }
}

// ---------------------------------------------------------------------------
// Grid barrier (device-scope). All blocks must be co-resident: grid = 250
// blocks x 256 threads, <=6KB LDS, fits 1 block/CU on 256 CUs.
// Release on arrive, acquire on spin (agent scope handles cross-XCD L2).
// ---------------------------------------------------------------------------
__device__ __forceinline__ void gbar(uint* bar, int nb, uint& phase) {
  __syncthreads();
  __threadfence();  // make this block's stores agent-visible
  ++phase;
  if (threadIdx.x == 0) {
    __hip_atomic_fetch_add(bar, 1u, __ATOMIC_RELEASE, __HIP_MEMORY_SCOPE_AGENT);
    uint tgt = (uint)nb * phase;
    while (__hip_atomic_load(bar, __ATOMIC_ACQUIRE, __HIP_MEMORY_SCOPE_AGENT) < tgt)
      __builtin_amdgcn_s_sleep(2);
  }
  __syncthreads();
  __threadfence();  // don't read stale lines from before the barrier
}

// ---------------------------------------------------------------------------
// Persistent GRU sequence kernel: runs all steps of a recurrence in ONE
// launch. Per step: phaseA (r,z gates) -> grid barrier -> phaseB (cand,
// state update) -> grid barrier. Replaces 2*steps kernel launches.
// ---------------------------------------------------------------------------
struct Seq {
  int steps;
  const float* Xr; const float* Xz; const float* Xc;  // [steps][32][1000]
  const ushort *Ur, *Uz, *U;                          // bf16 [1000][1024]
  const float *cr, *cz, *cc;                          // nullable ctx adds
  const float *br, *bz, *bb;
  float* h;          // state [32][1024] fp32 (padding stays 0)
  float* rh;         // r*h scratch [32][1024]
  float* zbuf;       // z scratch [32][1000]
  ushort* srm;       // if non-null: bf16 state log at (t+1)*32*1024
  uint* bar;
};

__global__ __launch_bounds__(256) void gru_seq(Seq a) {
  __shared__ float redA[4][4][2][32];
  __shared__ float redB[4][4][32];
  const int tid = threadIdx.x;
  const int w = tid >> 6, lane = tid & 63;
  const int b = lane & 31, kh = lane >> 5;
  const int j0 = blockIdx.x * 4;
  const int kbase = w * 256 + kh * 128;
  const int nb = gridDim.x;
  uint phase = 0;

  for (int t = 0; t < a.steps; ++t) {
    const float* Xr = a.Xr + t * 32000;
    const float* Xz = a.Xz + t * 32000;
    const float* Xc = a.Xc + t * 32000;

    // ---- phase A: pre_r = h@Ur^T, pre_z = h@Uz^T -> r*h, z ----
    {
      const float4* h4 = (const float4*)(a.h + b * HP_ + kbase);
      float accr[4] = {0.f, 0.f, 0.f, 0.f}, accz[4] = {0.f, 0.f, 0.f, 0.f};
#pragma unroll
      for (int i = 0; i < 16; ++i) {
        float4 ha = h4[2 * i], hb2 = h4[2 * i + 1];
        float hv[8] = {ha.x, ha.y, ha.z, ha.w, hb2.x, hb2.y, hb2.z, hb2.w};
        int k = kbase + i * 8;
#pragma unroll
        for (int j = 0; j < 4; ++j) {
          bf16x8 u = *(const bf16x8*)(a.Ur + (size_t)(j0 + j) * HP_ + k);
          bf16x8 v = *(const bf16x8*)(a.Uz + (size_t)(j0 + j) * HP_ + k);
#pragma unroll
          for (int e = 0; e < 8; ++e) {
            accr[j] = fmaf(hv[e], bf2f((ushort)u[e]), accr[j]);
            accz[j] = fmaf(hv[e], bf2f((ushort)v[e]), accz[j]);
          }
        }
      }
#pragma unroll
      for (int j = 0; j < 4; ++j) {
        float pr = accr[j] + __shfl_xor(accr[j], 32);
        float pz = accz[j] + __shfl_xor(accz[j], 32);
        if (lane < 32) {
          redA[w][j][0][b] = pr;
          redA[w][j][1][b] = pz;
        }
      }
      __syncthreads();
      {
        int eb = tid & 31, eg = (tid >> 5) & 1, ej = tid >> 6;
        float s = redA[0][ej][eg][eb] + redA[1][ej][eg][eb] +
                  redA[2][ej][eg][eb] + redA[3][ej][eg][eb];
        int j = j0 + ej;
        int o = eb * H_ + j;
        if (eg == 0) {
          float pre = s + Xr[o] + a.br[j] + (a.cr ? a.cr[o] : 0.f);
          float r = 1.f / (1.f + expf(-pre));
          a.rh[eb * HP_ + j] = r * a.h[eb * HP_ + j];
        } else {
          float pre = s + Xz[o] + a.bz[j] + (a.cz ? a.cz[o] : 0.f);
          a.zbuf[o] = 1.f / (1.f + expf(-pre));
        }
      }
    }
    gbar(a.bar, nb, phase);

    // ---- phase B: cand = tanh(rh@U^T + Xc + cc + b); s = (1-z)s + z*cand ----
    {
      const float4* h4 = (const float4*)(a.rh + b * HP_ + kbase);
      float acc[4] = {0.f, 0.f, 0.f, 0.f};
#pragma unroll
      for (int i = 0; i < 16; ++i) {
        float4 ha = h4[2 * i], hb2 = h4[2 * i + 1];
        float hv[8] = {ha.x, ha.y, ha.z, ha.w, hb2.x, hb2.y, hb2.z, hb2.w};
        int k = kbase + i * 8;
#pragma unroll
        for (int j = 0; j < 4; ++j) {
          bf16x8 u = *(const bf16x8*)(a.U + (size_t)(j0 + j) * HP_ + k);
#pragma unroll
          for (int e = 0; e < 8; ++e)
            acc[j] = fmaf(hv[e], bf2f((ushort)u[e]), acc[j]);
        }
      }
#pragma unroll
      for (int j = 0; j < 4; ++j) {
        float p = acc[j] + __shfl_xor(acc[j], 32);
        if (lane < 32) redB[w][j][b] = p;
      }
      __syncthreads();
      if (tid < 128) {
        int eb = tid & 31, ej = tid >> 5;
        float s = redB[0][ej][eb] + redB[1][ej][eb] + redB[2][ej][eb] + redB[3][ej][eb];
        int j = j0 + ej;
        int o = eb * H_ + j;
        float cand = tanhf(s + Xc[o] + a.bb[j] + (a.cc ? a.cc[o] : 0.f));
        float z = a.zbuf[o];
        float old = a.h[eb * HP_ + j];
        float nv = (1.f - z) * old + z * cand;
        a.h[eb * HP_ + j] = nv;
        if (a.srm) a.srm[(size_t)(t + 1) * B_ * HP_ + eb * HP_ + j] = f2bf(nv);
      }
    }
    if (t != a.steps - 1) gbar(a.bar, nb, phase);
    // final step: kernel-end release handles visibility for the next launch
  }
}

// ---------------------------------------------------------------------------
// context projections + s0 (bf16 weights)
// ---------------------------------------------------------------------------
struct Ctx16 {
  const ushort* W[5];
  float* out[5];
  int mode[5];
  const float* x;
  float* hbk2;
  ushort* srm0;
};

__global__ __launch_bounds__(256) void ctx_mv16(Ctx16 a) {
  __shared__ float red[4][4][32];
  const int z = blockIdx.z;
  const ushort* __restrict__ W = a.W[z];
  const float* __restrict__ x = a.x;
  const int tid = threadIdx.x;
  const int w = tid >> 6, lane = tid & 63;
  const int b = lane & 31, kh = lane >> 5;
  const int j0 = blockIdx.x * 4;
  const int kbase = w * 256 + kh * 128;
  const float4* h4 = (const float4*)(x + b * HP_ + kbase);
  float acc[4] = {0.f, 0.f, 0.f, 0.f};
#pragma unroll
  for (int i = 0; i < 16; ++i) {
    float4 ha = h4[2 * i], hb = h4[2 * i + 1];
    float hv[8] = {ha.x, ha.y, ha.z, ha.w, hb.x, hb.y, hb.z, hb.w};
    int k = kbase + i * 8;
#pragma unroll
    for (int j = 0; j < 4; ++j) {
      bf16x8 u = *(const bf16x8*)(W + (size_t)(j0 + j) * HP_ + k);
#pragma unroll
      for (int e = 0; e < 8; ++e)
        acc[j] = fmaf(hv[e], bf2f((ushort)u[e]), acc[j]);
    }
  }
  float p[4];
#pragma unroll
  for (int j = 0; j < 4; ++j) p[j] = acc[j] + __shfl_xor(acc[j], 32);
  if (lane < 32) {
#pragma unroll
    for (int j = 0; j < 4; ++j) red[w][j][b] = p[j];
  }
  __syncthreads();
  if (tid < 128) {
    int eb = tid & 31, ej = tid >> 5;
    float s = red[0][ej][eb] + red[1][ej][eb] + red[2][ej][eb] + red[3][ej][eb];
    int j = j0 + ej;
    if (a.mode[z] == 0) {
      a.out[z][eb * H_ + j] = s;
    } else {
      float v = tanhf(s);
      a.hbk2[eb * HP_ + j] = v;
      a.srm0[eb * HP_ + j] = f2bf(v);
    }
  }
}

// ---------------------------------------------------------------------------
// Host
// ---------------------------------------------------------------------------
extern "C" void kernel_launch(void* const* d_in, const int* in_sizes, int n_in,
                              void* d_out, int out_size, void* d_ws, size_t ws_size,
                              hipStream_t stream) {
  const int*   src     = (const int*)d_in[0];
  const int*   tgt     = (const int*)d_in[1];
  const float* src_emb = (const float*)d_in[3];
  const float* tgt_emb = (const float*)d_in[4];
  const float* enc_W   = (const float*)d_in[5];
  const float* enc_Wz  = (const float*)d_in[6];
  const float* enc_Wr  = (const float*)d_in[7];
  const float* enc_U   = (const float*)d_in[8];
  const float* enc_Uz  = (const float*)d_in[9];
  const float* enc_Ur  = (const float*)d_in[10];
  const float* enc_b   = (const float*)d_in[11];
  const float* enc_bz  = (const float*)d_in[12];
  const float* enc_br  = (const float*)d_in[13];
  const float* dec_W   = (const float*)d_in[14];
  const float* dec_Wz  = (const float*)d_in[15];
  const float* dec_Wr  = (const float*)d_in[16];
  const float* dec_U   = (const float*)d_in[17];
  const float* dec_Uz  = (const float*)d_in[18];
  const float* dec_Ur  = (const float*)d_in[19];
  const float* dec_C   = (const float*)d_in[20];
  const float* dec_Cz  = (const float*)d_in[21];
  const float* dec_Cr  = (const float*)d_in[22];
  const float* dec_b   = (const float*)d_in[23];
  const float* dec_bz  = (const float*)d_in[24];
  const float* dec_br  = (const float*)d_in[25];
  const float* W_s     = (const float*)d_in[26];
  const float* U_o     = (const float*)d_in[27];
  const float* V_o     = (const float*)d_in[28];
  const float* C_o     = (const float*)d_in[29];
  const float* W_o     = (const float*)d_in[30];
  float* out = (float*)d_out;
  char* wsb = (char*)d_ws;
  (void)in_sizes; (void)n_in; (void)out_size; (void)ws_size;

  // byte-offset workspace layout
  float*  hbk   = (float*)(wsb + 0);         // 32x1024
  float*  rhbk  = (float*)(wsb + 131072);
  float*  hbk2  = (float*)(wsb + 262144);
  ushort* Srm16 = (ushort*)(wsb + 393216);   // 768x1024 bf16
  ushort* Tmax  = (ushort*)(wsb + 1966080);  // 768x512 bf16
  // zero block ends at 2752512
  float*  zb    = (float*)(wsb + 2752512);   // 32x1000
  float*  cCr   = (float*)(wsb + 2880512);
  float*  cCz   = (float*)(wsb + 3008512);
  float*  cC    = (float*)(wsb + 3136512);
  float*  cCo   = (float*)(wsb + 3264512);
  float*  YV    = (float*)(wsb + 3392512);   // 768x1000
  float*  XPr   = (float*)(wsb + 6464512);
  float*  XPz   = (float*)(wsb + 9536512);
  float*  XPc   = (float*)(wsb + 12608512);
  float*  YPr   = (float*)(wsb + 15680512);
  float*  YPz   = (float*)(wsb + 18752512);
  float*  YPc   = (float*)(wsb + 21824512);
  ushort* XE16  = (ushort*)(wsb + 24896512); // 768x640 bf16
  ushort* YE16  = (ushort*)(wsb + 25879552);
  ushort* H16   = (ushort*)(wsb + 26862592); // 12 x 1000x1024 bf16
  ushort* E16   = (ushort*)(wsb + 51438592); // 7 x 1000x640 bf16
  ushort* Wo16  = (ushort*)(wsb + 60398592); // 30000x512 bf16

  // barrier counters: first 128B of out, fully overwritten by logits GEMM
  uint* barE = (uint*)((char*)d_out + 0);
  uint* barD = (uint*)((char*)d_out + 64);

  // zero: state buffers + Srm16 pads + Tmax pads; barrier counters
  hipMemsetAsync(wsb, 0, 2752512, stream);
  hipMemsetAsync(d_out, 0, 128, stream);

  // ---- weight conversions (per call; ws is re-poisoned each call) ----
  {
    ConvJobs a = {};
    const float* hin[12] = {enc_Ur, enc_Uz, enc_U, dec_Ur, dec_Uz, dec_U,
                            dec_Cr, dec_Cz, dec_C, C_o, W_s, U_o};
    const float* ein[7]  = {enc_Wr, enc_Wz, enc_W, dec_Wr, dec_Wz, dec_W, V_o};
    for (int i = 0; i < 12; ++i) {
      a.in[i] = hin[i]; a.out[i] = H16 + (size_t)i * 1000 * HP_;
      a.K[i] = H_; a.Kp[i] = HP_;
    }
    for (int i = 0; i < 7; ++i) {
      a.in[12 + i] = ein[i]; a.out[12 + i] = E16 + (size_t)i * 1000 * EP_;
      a.K[12 + i] = E_; a.Kp[12 + i] = EP_;
    }
    conv_small<<<dim3(1000, 19), dim3(256), 0, stream>>>(a);
  }
  conv_wo<<<dim3(V_), dim3(256), 0, stream>>>(W_o, Wo16);

  gather16<<<dim3(2 * S_ * B_), dim3(256), 0, stream>>>(src, tgt, src_emb, tgt_emb, XE16, YE16);

  // ---- batched input projections (MFMA): M=768 N=1000 Kp=640 ----
  {
    MG g = {};
    const ushort* As[7] = {XE16, XE16, XE16, YE16, YE16, YE16, YE16};
    float* Cs[7] = {XPr, XPz, XPc, YPr, YPz, YPc, YV};
    for (int i = 0; i < 7; ++i) {
      g.A[i] = As[i]; g.Bw[i] = E16 + (size_t)i * 1000 * EP_; g.C[i] = Cs[i];
    }
    g.M = S_ * B_; g.N = H_; g.Kp = EP_; g.ldc = H_; g.mode = 0;
    mgemm<<<dim3(8, 6, 7), dim3(256), 0, stream>>>(g);
  }

  const ushort* encUr16 = H16 + 0 * 1024000;
  const ushort* encUz16 = H16 + 1 * 1024000;
  const ushort* encU16  = H16 + 2 * 1024000;
  const ushort* decUr16 = H16 + 3 * 1024000;
  const ushort* decUz16 = H16 + 4 * 1024000;
  const ushort* decU16  = H16 + 5 * 1024000;
  const ushort* Uo16    = H16 + 11 * 1024000;

  // ---- encoder recurrence: ONE persistent launch, 24 steps ----
  {
    Seq a = {};
    a.steps = S_;
    a.Xr = XPr; a.Xz = XPz; a.Xc = XPc;
    a.Ur = encUr16; a.Uz = encUz16; a.U = encU16;
    a.cr = nullptr; a.cz = nullptr; a.cc = nullptr;
    a.br = enc_br; a.bz = enc_bz; a.bb = enc_b;
    a.h = hbk; a.rh = rhbk; a.zbuf = zb;
    a.srm = nullptr; a.bar = barE;
    gru_seq<<<dim3(250), dim3(256), 0, stream>>>(a);
  }

  // ---- context projections + s0 ----
  {
    Ctx16 a = {};
    for (int i = 0; i < 5; ++i) {
      a.W[i] = H16 + (size_t)(6 + i) * 1024000;
      a.mode[i] = (i == 4) ? 2 : 0;
    }
    a.out[0] = cCr; a.out[1] = cCz; a.out[2] = cC; a.out[3] = cCo; a.out[4] = nullptr;
    a.x = hbk; a.hbk2 = hbk2; a.srm0 = Srm16;
    ctx_mv16<<<dim3(250, 1, 5), dim3(256), 0, stream>>>(a);
  }

  // ---- decoder recurrence: ONE persistent launch, 23 steps ----
  {
    Seq a = {};
    a.steps = T_ - 1;
    a.Xr = YPr; a.Xz = YPz; a.Xc = YPc;
    a.Ur = decUr16; a.Uz = decUz16; a.U = decU16;
    a.cr = cCr; a.cz = cCz; a.cc = cC;
    a.br = dec_br; a.bz = dec_bz; a.bb = dec_b;
    a.h = hbk2; a.rh = rhbk; a.zbuf = zb;
    a.srm = Srm16; a.bar = barD;
    gru_seq<<<dim3(250), dim3(256), 0, stream>>>(a);
  }

  // ---- maxout GEMM: t = Srm@U_o^T + YV + cCo -> Tmax bf16 [768][512] ----
  {
    MG g = {};
    g.A[0] = Srm16; g.Bw[0] = Uo16;
    g.M = T_ * B_; g.N = M2_; g.Kp = HP_; g.ldc = 0; g.mode = 1;
    g.e1 = YV; g.e2 = cCo; g.tmax = Tmax;
    mgemm<<<dim3(8, 6, 1), dim3(256), 0, stream>>>(g);
  }

  // ---- logits = Tmax @ W_o^T -> out[b][t][v] ----
  {
    MG g = {};
    g.A[0] = Tmax; g.Bw[0] = Wo16; g.C[0] = out;
    g.M = T_ * B_; g.N = V_; g.Kp = KW_; g.ldc = V_; g.mode = 2;
    mgemm<<<dim3(235, 6, 1), dim3(256), 0, stream>>>(g);
  }
}

// Round 2
// 5052.419 us; speedup vs baseline: 1.3627x; 1.3627x over previous
//
#include <hip/hip_runtime.h>
#include <math.h>

typedef unsigned short ushort;
typedef unsigned int uint;
typedef __attribute__((ext_vector_type(8))) short bf16x8;
typedef __attribute__((ext_vector_type(4))) float f32x4;

#define B_  32
#define S_  24
#define T_  24
#define E_  620
#define EP_ 640
#define H_  1000
#define HP_ 1024
#define V_  30000
#define M2_ 1000
#define KW_ 512

__device__ __forceinline__ ushort f2bf(float f) {
  uint u = __float_as_uint(f);
  u += 0x7FFFu + ((u >> 16) & 1u);
  return (ushort)(u >> 16);
}
__device__ __forceinline__ float bf2f(ushort s) {
  return __uint_as_float(((uint)s) << 16);
}

// ---------------------------------------------------------------------------
// weight conversion: fp32 [N][K] -> bf16 [N][Kp] zero-padded
// ---------------------------------------------------------------------------
struct ConvJobs {
  const float* in[19];
  ushort* out[19];
  int K[19], Kp[19];
};
__global__ __launch_bounds__(256) void conv_small(ConvJobs a) {
  int j = blockIdx.y, row = blockIdx.x;
  const float* ip = a.in[j] + (size_t)row * a.K[j];
  ushort* op = a.out[j] + (size_t)row * a.Kp[j];
  for (int k = threadIdx.x; k < a.Kp[j]; k += 256)
    op[k] = (k < a.K[j]) ? f2bf(ip[k]) : (ushort)0;
}

__global__ __launch_bounds__(256) void conv_wo(const float* __restrict__ in,
                                               ushort* __restrict__ out) {
  int row = blockIdx.x;
  const float* ip = in + (size_t)row * 500;
  ushort* op = out + (size_t)row * 512;
  int k = threadIdx.x;
  op[k] = (k < 500) ? f2bf(ip[k]) : (ushort)0;
  k += 256;
  op[k] = (k < 500) ? f2bf(ip[k]) : (ushort)0;
}

// ---------------------------------------------------------------------------
// embedding gather -> bf16, K padded 620->640
// ---------------------------------------------------------------------------
__global__ __launch_bounds__(256) void gather16(
    const int* __restrict__ src, const int* __restrict__ tgt,
    const float* __restrict__ semb, const float* __restrict__ temb,
    ushort* __restrict__ XE, ushort* __restrict__ YE) {
  int row = blockIdx.x;
  int isT = row >= S_ * B_;
  int r = isT ? row - S_ * B_ : row;
  int st = r >> 5, b = r & 31;
  int tok = isT ? tgt[b * T_ + st] : src[b * S_ + st];
  const float* e = (isT ? temb : semb) + (size_t)tok * E_;
  ushort* o = (isT ? YE : XE) + (size_t)r * EP_;
  for (int k = threadIdx.x; k < EP_; k += 256)
    o[k] = (k < E_) ? f2bf(e[k]) : (ushort)0;
}

// ---------------------------------------------------------------------------
// bf16 MFMA GEMM: C = A @ Bw^T. A [M][Kp] bf16, Bw [N][Kp] bf16.
// 128x128 tile, 4 waves, each 64x64 (4x4 frags of 16x16x32).
// Register-staged double buffer: prefetch tile k+1 into VGPRs during MFMA of
// tile k.
// mode 0: fp32 store C[row][col] (ldc)
// mode 1: maxout: v = acc+e1[row][col]+e2[row&31][col]; pair-max -> bf16 tmax
// mode 2: scatter: row=t*32+b -> C[(b*T+t)*ldc + col]
// ---------------------------------------------------------------------------
struct MG {
  const ushort* A[8];
  const ushort* Bw[8];
  float* C[8];
  int M, N, Kp, ldc;
  int mode;
  const float* e1;
  const float* e2;
  ushort* tmax;
};

__global__ __launch_bounds__(256) void mgemm(MG g) {
  __shared__ ushort As[128 * 40];
  __shared__ ushort Bs[128 * 40];
  const int z = blockIdx.z;
  const ushort* __restrict__ A = g.A[z];
  const ushort* __restrict__ Bw = g.Bw[z];
  const int tid = threadIdx.x;
  const int wave = tid >> 6, lane = tid & 63;
  const int lm = lane & 15, kq = lane >> 4;
  const int wm = (wave >> 1) * 64, wn = (wave & 1) * 64;
  const int m0 = blockIdx.y * 128, n0 = blockIdx.x * 128;
  const int Kp = g.Kp;

  f32x4 acc[4][4];
#pragma unroll
  for (int i = 0; i < 4; ++i)
#pragma unroll
    for (int j = 0; j < 4; ++j) acc[i][j] = (f32x4){0.f, 0.f, 0.f, 0.f};

  const int row_s = tid >> 2, seg = tid & 3;

  uint4 va[2], vb[2];
  auto ld = [&](int k0) {
#pragma unroll
    for (int p = 0; p < 2; ++p) {
      int gm = m0 + row_s + p * 64;
      va[p] = make_uint4(0, 0, 0, 0);
      if (gm < g.M) va[p] = *(const uint4*)(A + (size_t)gm * Kp + k0 + seg * 8);
      int gn = n0 + row_s + p * 64;
      vb[p] = make_uint4(0, 0, 0, 0);
      if (gn < g.N) vb[p] = *(const uint4*)(Bw + (size_t)gn * Kp + k0 + seg * 8);
    }
  };

  ld(0);
  for (int k0 = 0; k0 < Kp; k0 += 32) {
#pragma unroll
    for (int p = 0; p < 2; ++p) {
      int row = row_s + p * 64;
      *(uint4*)&As[row * 40 + seg * 8] = va[p];
      *(uint4*)&Bs[row * 40 + seg * 8] = vb[p];
    }
    __syncthreads();
    if (k0 + 32 < Kp) ld(k0 + 32);  // issue next-tile loads under the MFMAs
    bf16x8 af[4], bfr[4];
#pragma unroll
    for (int i = 0; i < 4; ++i)
      af[i] = *(const bf16x8*)&As[(wm + i * 16 + lm) * 40 + kq * 8];
#pragma unroll
    for (int j = 0; j < 4; ++j)
      bfr[j] = *(const bf16x8*)&Bs[(wn + j * 16 + lm) * 40 + kq * 8];
#pragma unroll
    for (int i = 0; i < 4; ++i)
#pragma unroll
      for (int j = 0; j < 4; ++j)
        acc[i][j] = __builtin_amdgcn_mfma_f32_16x16x32_bf16(af[i], bfr[j], acc[i][j], 0, 0, 0);
    __syncthreads();
  }

#pragma unroll
  for (int i = 0; i < 4; ++i) {
    int grow = m0 + wm + i * 16 + kq * 4;
#pragma unroll
    for (int j = 0; j < 4; ++j) {
      int gcol = n0 + wn + j * 16 + lm;
#pragma unroll
      for (int r = 0; r < 4; ++r) {
        int row = grow + r;
        float v = acc[i][j][r];
        if (g.mode == 0) {
          if (row < g.M && gcol < g.N) g.C[z][(size_t)row * g.ldc + gcol] = v;
        } else if (g.mode == 1) {
          float vv = v;
          if (row < g.M && gcol < g.N)
            vv += g.e1[(size_t)row * M2_ + gcol] + g.e2[(size_t)(row & 31) * M2_ + gcol];
          float other = __shfl_xor(vv, 1);
          if ((lane & 1) == 0 && row < g.M && gcol < g.N)
            g.tmax[(size_t)row * KW_ + (gcol >> 1)] = f2bf(fmaxf(vv, other));
        } else {
          if (row < g.M && gcol < g.N) {
            int t = row >> 5, b = row & 31;
            g.C[z][((size_t)b * T_ + t) * (size_t)g.ldc + gcol] = v;
          }
        }
      }
    }
  }
}

// ---------------------------------------------------------------------------
// Grid barrier. Release add (flushes this XCD's dirty L2 lines), RELAXED
// spin (no per-iteration cache invalidate!), one acquire fence after exit.
// All per-step operands live in LDS, which the fence cannot invalidate —
// only h/rh (the true cross-block exchange) pays the coherence cost.
// ---------------------------------------------------------------------------
__device__ __forceinline__ void gbar(uint* bar, int nb, uint& phase) {
  __syncthreads();
  __threadfence();  // release: make this block's stores agent-visible
  ++phase;
  if (threadIdx.x == 0) {
    __hip_atomic_fetch_add(bar, 1u, __ATOMIC_RELEASE, __HIP_MEMORY_SCOPE_AGENT);
    uint tgt = (uint)nb * phase;
    while (__hip_atomic_load(bar, __ATOMIC_RELAXED, __HIP_MEMORY_SCOPE_AGENT) < tgt)
      __builtin_amdgcn_s_sleep(8);
  }
  __syncthreads();
  __builtin_amdgcn_fence(__ATOMIC_ACQUIRE, "agent");  // invalidate stale lines
}

// ---------------------------------------------------------------------------
// Persistent GRU sequence kernel. ONE launch per recurrence.
// Everything re-read per step is LDS-resident (loaded once at kernel start):
//   - weights Ur/Uz/U rows j0..j0+3  (24 KB bf16)
//   - X projections for ALL steps    (36 KB fp32)
//   - ctx adds + biases              (1.6 KB)
//   - z gate (block-local!)          (512 B)
// Only h (phase A in / phase B out) and rh (A out / B in) cross blocks.
// ---------------------------------------------------------------------------
struct Seq {
  int steps;
  const float* Xr; const float* Xz; const float* Xc;  // [steps][32][1000]
  const ushort *Ur, *Uz, *U;                          // bf16 [1000][1024]
  const float *cr, *cz, *cc;                          // nullable ctx adds
  const float *br, *bz, *bb;
  float* h;          // state [32][1024] fp32 (padding stays 0)
  float* rh;         // r*h scratch [32][1024]
  ushort* srm;       // if non-null: bf16 state log at (t+1)*32*1024
  uint* bar;
};

__global__ __launch_bounds__(256) void gru_seq(Seq a) {
  __shared__ ushort Wlds[3 * 4 * 1024];   // [mat][row 0..3][k 0..1023]
  __shared__ float  Xlds[24 * 384];       // [t][mat][eb*4+ej]
  __shared__ float  redA[4][4][2][32];
  __shared__ float  redB[4][4][32];
  __shared__ float  Clds[3][128];         // ctx adds [mat][eb*4+ej]
  __shared__ float  blds[3][4];           // biases   [mat][ej]
  __shared__ float  zlds[128];            // z gate   [eb*4+ej] (block-local)

  const int tid = threadIdx.x;
  const int w = tid >> 6, lane = tid & 63;
  const int b = lane & 31, kh = lane >> 5;
  const int j0 = blockIdx.x * 4;
  const int kbase = w * 256 + kh * 128;
  const int nb = gridDim.x;
  uint phase = 0;

  // epilogue thread mapping
  const int eb = tid & 31;
  const int eg = (tid >> 5) & 1;   // phase A: 0 -> r-gate, 1 -> z-gate
  const int ejA = tid >> 6;        // phase A output col within block
  const int exA = eb * 4 + ejA;
  const int ejB = (tid >> 5) & 3;  // phase B (tid<128) col within block
  const int exB = eb * 4 + ejB;

  // ---- one-time preload: weights -> LDS (bf16) ----
  {
    const ushort* Ws[3] = {a.Ur, a.Uz, a.U};
    for (int q = tid; q < 3 * 4 * 128; q += 256) {
      int mat = q >> 9;
      int rem = q & 511;
      int row = rem >> 7;
      int k8 = (rem & 127) << 3;
      *(bf16x8*)&Wlds[mat * 4096 + row * 1024 + k8] =
          *(const bf16x8*)(Ws[mat] + (size_t)(j0 + row) * HP_ + k8);
    }
  }
  // ---- one-time preload: X projections, all steps ----
  for (int q = tid; q < a.steps * 384; q += 256) {
    int t = q / 384;
    int rem = q - t * 384;
    int mat = rem >> 7;
    int r2 = rem & 127;
    const float* Xs = (mat == 0 ? a.Xr : mat == 1 ? a.Xz : a.Xc) + t * 32000;
    Xlds[q] = Xs[(r2 >> 2) * H_ + j0 + (r2 & 3)];
  }
  // ---- one-time preload: ctx adds + biases ----
  if (a.cr) {
    const float* Cs[3] = {a.cr, a.cz, a.cc};
    for (int q = tid; q < 3 * 128; q += 256) {
      int mat = q >> 7, r2 = q & 127;
      Clds[mat][r2] = Cs[mat][(r2 >> 2) * H_ + j0 + (r2 & 3)];
    }
  } else {
    for (int q = tid; q < 3 * 128; q += 256) Clds[q >> 7][q & 127] = 0.f;
  }
  if (tid < 12) {
    const float* bs[3] = {a.br, a.bz, a.bb};
    blds[tid >> 2][tid & 3] = bs[tid >> 2][j0 + (tid & 3)];
  }
  __syncthreads();

  for (int t = 0; t < a.steps; ++t) {
    // ---- phase A: pre_r = h@Ur^T, pre_z = h@Uz^T -> rh, z ----
    {
      float xA = Xlds[t * 384 + eg * 128 + exA];
      const float4* h4 = (const float4*)(a.h + b * HP_ + kbase);
      float accr[4] = {0.f, 0.f, 0.f, 0.f}, accz[4] = {0.f, 0.f, 0.f, 0.f};
#pragma unroll
      for (int i = 0; i < 16; ++i) {
        float4 ha = h4[2 * i], hb2 = h4[2 * i + 1];
        float hv[8] = {ha.x, ha.y, ha.z, ha.w, hb2.x, hb2.y, hb2.z, hb2.w};
        int k = kbase + i * 8;
#pragma unroll
        for (int j = 0; j < 4; ++j) {
          bf16x8 u = *(const bf16x8*)&Wlds[j * 1024 + k];
          bf16x8 v = *(const bf16x8*)&Wlds[4096 + j * 1024 + k];
#pragma unroll
          for (int e = 0; e < 8; ++e) {
            accr[j] = fmaf(hv[e], bf2f((ushort)u[e]), accr[j]);
            accz[j] = fmaf(hv[e], bf2f((ushort)v[e]), accz[j]);
          }
        }
      }
#pragma unroll
      for (int j = 0; j < 4; ++j) {
        float pr = accr[j] + __shfl_xor(accr[j], 32);
        float pz = accz[j] + __shfl_xor(accz[j], 32);
        if (lane < 32) {
          redA[w][j][0][b] = pr;
          redA[w][j][1][b] = pz;
        }
      }
      __syncthreads();
      {
        float s = redA[0][ejA][eg][eb] + redA[1][ejA][eg][eb] +
                  redA[2][ejA][eg][eb] + redA[3][ejA][eg][eb];
        int j = j0 + ejA;
        float pre = s + xA + blds[eg][ejA] + Clds[eg][exA];
        float sg = 1.f / (1.f + expf(-pre));
        if (eg == 0) {
          a.rh[eb * HP_ + j] = sg * a.h[eb * HP_ + j];
        } else {
          zlds[exA] = sg;
        }
      }
    }
    gbar(a.bar, nb, phase);

    // ---- phase B: cand = tanh(rh@U^T + Xc + cc + b); h = (1-z)h + z*cand ----
    {
      float xB = (tid < 128) ? Xlds[t * 384 + 256 + exB] : 0.f;
      const float4* h4 = (const float4*)(a.rh + b * HP_ + kbase);
      float acc[4] = {0.f, 0.f, 0.f, 0.f};
#pragma unroll
      for (int i = 0; i < 16; ++i) {
        float4 ha = h4[2 * i], hb2 = h4[2 * i + 1];
        float hv[8] = {ha.x, ha.y, ha.z, ha.w, hb2.x, hb2.y, hb2.z, hb2.w};
        int k = kbase + i * 8;
#pragma unroll
        for (int j = 0; j < 4; ++j) {
          bf16x8 u = *(const bf16x8*)&Wlds[8192 + j * 1024 + k];
#pragma unroll
          for (int e = 0; e < 8; ++e)
            acc[j] = fmaf(hv[e], bf2f((ushort)u[e]), acc[j]);
        }
      }
#pragma unroll
      for (int j = 0; j < 4; ++j) {
        float p = acc[j] + __shfl_xor(acc[j], 32);
        if (lane < 32) redB[w][j][b] = p;
      }
      __syncthreads();
      if (tid < 128) {
        float s = redB[0][ejB][eb] + redB[1][ejB][eb] +
                  redB[2][ejB][eb] + redB[3][ejB][eb];
        int j = j0 + ejB;
        float cand = tanhf(s + xB + blds[2][ejB] + Clds[2][exB]);
        float z = zlds[exB];
        float old = a.h[eb * HP_ + j];
        float nv = (1.f - z) * old + z * cand;
        a.h[eb * HP_ + j] = nv;
        if (a.srm) a.srm[(size_t)(t + 1) * B_ * HP_ + eb * HP_ + j] = f2bf(nv);
      }
    }
    if (t != a.steps - 1) gbar(a.bar, nb, phase);
    // final step: kernel-end flush handles visibility for the next launch
  }
}

// ---------------------------------------------------------------------------
// context projections + s0 (bf16 weights)
// ---------------------------------------------------------------------------
struct Ctx16 {
  const ushort* W[5];
  float* out[5];
  int mode[5];
  const float* x;
  float* hbk2;
  ushort* srm0;
};

__global__ __launch_bounds__(256) void ctx_mv16(Ctx16 a) {
  __shared__ float red[4][4][32];
  const int z = blockIdx.z;
  const ushort* __restrict__ W = a.W[z];
  const float* __restrict__ x = a.x;
  const int tid = threadIdx.x;
  const int w = tid >> 6, lane = tid & 63;
  const int b = lane & 31, kh = lane >> 5;
  const int j0 = blockIdx.x * 4;
  const int kbase = w * 256 + kh * 128;
  const float4* h4 = (const float4*)(x + b * HP_ + kbase);
  float acc[4] = {0.f, 0.f, 0.f, 0.f};
#pragma unroll
  for (int i = 0; i < 16; ++i) {
    float4 ha = h4[2 * i], hb = h4[2 * i + 1];
    float hv[8] = {ha.x, ha.y, ha.z, ha.w, hb.x, hb.y, hb.z, hb.w};
    int k = kbase + i * 8;
#pragma unroll
    for (int j = 0; j < 4; ++j) {
      bf16x8 u = *(const bf16x8*)(W + (size_t)(j0 + j) * HP_ + k);
#pragma unroll
      for (int e = 0; e < 8; ++e)
        acc[j] = fmaf(hv[e], bf2f((ushort)u[e]), acc[j]);
    }
  }
  float p[4];
#pragma unroll
  for (int j = 0; j < 4; ++j) p[j] = acc[j] + __shfl_xor(acc[j], 32);
  if (lane < 32) {
#pragma unroll
    for (int j = 0; j < 4; ++j) red[w][j][b] = p[j];
  }
  __syncthreads();
  if (tid < 128) {
    int eb = tid & 31, ej = tid >> 5;
    float s = red[0][ej][eb] + red[1][ej][eb] + red[2][ej][eb] + red[3][ej][eb];
    int j = j0 + ej;
    if (a.mode[z] == 0) {
      a.out[z][eb * H_ + j] = s;
    } else {
      float v = tanhf(s);
      a.hbk2[eb * HP_ + j] = v;
      a.srm0[eb * HP_ + j] = f2bf(v);
    }
  }
}

// ---------------------------------------------------------------------------
// Host
// ---------------------------------------------------------------------------
extern "C" void kernel_launch(void* const* d_in, const int* in_sizes, int n_in,
                              void* d_out, int out_size, void* d_ws, size_t ws_size,
                              hipStream_t stream) {
  const int*   src     = (const int*)d_in[0];
  const int*   tgt     = (const int*)d_in[1];
  const float* src_emb = (const float*)d_in[3];
  const float* tgt_emb = (const float*)d_in[4];
  const float* enc_W   = (const float*)d_in[5];
  const float* enc_Wz  = (const float*)d_in[6];
  const float* enc_Wr  = (const float*)d_in[7];
  const float* enc_U   = (const float*)d_in[8];
  const float* enc_Uz  = (const float*)d_in[9];
  const float* enc_Ur  = (const float*)d_in[10];
  const float* enc_b   = (const float*)d_in[11];
  const float* enc_bz  = (const float*)d_in[12];
  const float* enc_br  = (const float*)d_in[13];
  const float* dec_W   = (const float*)d_in[14];
  const float* dec_Wz  = (const float*)d_in[15];
  const float* dec_Wr  = (const float*)d_in[16];
  const float* dec_U   = (const float*)d_in[17];
  const float* dec_Uz  = (const float*)d_in[18];
  const float* dec_Ur  = (const float*)d_in[19];
  const float* dec_C   = (const float*)d_in[20];
  const float* dec_Cz  = (const float*)d_in[21];
  const float* dec_Cr  = (const float*)d_in[22];
  const float* dec_b   = (const float*)d_in[23];
  const float* dec_bz  = (const float*)d_in[24];
  const float* dec_br  = (const float*)d_in[25];
  const float* W_s     = (const float*)d_in[26];
  const float* U_o     = (const float*)d_in[27];
  const float* V_o     = (const float*)d_in[28];
  const float* C_o     = (const float*)d_in[29];
  const float* W_o     = (const float*)d_in[30];
  float* out = (float*)d_out;
  char* wsb = (char*)d_ws;
  (void)in_sizes; (void)n_in; (void)out_size; (void)ws_size;

  // byte-offset workspace layout
  float*  hbk   = (float*)(wsb + 0);         // 32x1024
  float*  rhbk  = (float*)(wsb + 131072);
  float*  hbk2  = (float*)(wsb + 262144);
  ushort* Srm16 = (ushort*)(wsb + 393216);   // 768x1024 bf16
  ushort* Tmax  = (ushort*)(wsb + 1966080);  // 768x512 bf16
  // zero block ends at 2752512
  float*  cCr   = (float*)(wsb + 2880512);
  float*  cCz   = (float*)(wsb + 3008512);
  float*  cC    = (float*)(wsb + 3136512);
  float*  cCo   = (float*)(wsb + 3264512);
  float*  YV    = (float*)(wsb + 3392512);   // 768x1000
  float*  XPr   = (float*)(wsb + 6464512);
  float*  XPz   = (float*)(wsb + 9536512);
  float*  XPc   = (float*)(wsb + 12608512);
  float*  YPr   = (float*)(wsb + 15680512);
  float*  YPz   = (float*)(wsb + 18752512);
  float*  YPc   = (float*)(wsb + 21824512);
  ushort* XE16  = (ushort*)(wsb + 24896512); // 768x640 bf16
  ushort* YE16  = (ushort*)(wsb + 25879552);
  ushort* H16   = (ushort*)(wsb + 26862592); // 12 x 1000x1024 bf16
  ushort* E16   = (ushort*)(wsb + 51438592); // 7 x 1000x640 bf16
  ushort* Wo16  = (ushort*)(wsb + 60398592); // 30000x512 bf16

  // barrier counters: first 128B of out, fully overwritten by logits GEMM
  uint* barE = (uint*)((char*)d_out + 0);
  uint* barD = (uint*)((char*)d_out + 64);

  // zero: state buffers + Srm16 pads + Tmax pads; barrier counters
  hipMemsetAsync(wsb, 0, 2752512, stream);
  hipMemsetAsync(d_out, 0, 128, stream);

  // ---- weight conversions (per call; ws is re-poisoned each call) ----
  {
    ConvJobs a = {};
    const float* hin[12] = {enc_Ur, enc_Uz, enc_U, dec_Ur, dec_Uz, dec_U,
                            dec_Cr, dec_Cz, dec_C, C_o, W_s, U_o};
    const float* ein[7]  = {enc_Wr, enc_Wz, enc_W, dec_Wr, dec_Wz, dec_W, V_o};
    for (int i = 0; i < 12; ++i) {
      a.in[i] = hin[i]; a.out[i] = H16 + (size_t)i * 1000 * HP_;
      a.K[i] = H_; a.Kp[i] = HP_;
    }
    for (int i = 0; i < 7; ++i) {
      a.in[12 + i] = ein[i]; a.out[12 + i] = E16 + (size_t)i * 1000 * EP_;
      a.K[12 + i] = E_; a.Kp[12 + i] = EP_;
    }
    conv_small<<<dim3(1000, 19), dim3(256), 0, stream>>>(a);
  }
  conv_wo<<<dim3(V_), dim3(256), 0, stream>>>(W_o, Wo16);

  gather16<<<dim3(2 * S_ * B_), dim3(256), 0, stream>>>(src, tgt, src_emb, tgt_emb, XE16, YE16);

  // ---- batched input projections (MFMA): M=768 N=1000 Kp=640 ----
  {
    MG g = {};
    const ushort* As[7] = {XE16, XE16, XE16, YE16, YE16, YE16, YE16};
    float* Cs[7] = {XPr, XPz, XPc, YPr, YPz, YPc, YV};
    for (int i = 0; i < 7; ++i) {
      g.A[i] = As[i]; g.Bw[i] = E16 + (size_t)i * 1000 * EP_; g.C[i] = Cs[i];
    }
    g.M = S_ * B_; g.N = H_; g.Kp = EP_; g.ldc = H_; g.mode = 0;
    mgemm<<<dim3(8, 6, 7), dim3(256), 0, stream>>>(g);
  }

  const ushort* encUr16 = H16 + 0 * 1024000;
  const ushort* encUz16 = H16 + 1 * 1024000;
  const ushort* encU16  = H16 + 2 * 1024000;
  const ushort* decUr16 = H16 + 3 * 1024000;
  const ushort* decUz16 = H16 + 4 * 1024000;
  const ushort* decU16  = H16 + 5 * 1024000;
  const ushort* Uo16    = H16 + 11 * 1024000;

  // ---- encoder recurrence: ONE persistent launch, 24 steps ----
  {
    Seq a = {};
    a.steps = S_;
    a.Xr = XPr; a.Xz = XPz; a.Xc = XPc;
    a.Ur = encUr16; a.Uz = encUz16; a.U = encU16;
    a.cr = nullptr; a.cz = nullptr; a.cc = nullptr;
    a.br = enc_br; a.bz = enc_bz; a.bb = enc_b;
    a.h = hbk; a.rh = rhbk;
    a.srm = nullptr; a.bar = barE;
    gru_seq<<<dim3(250), dim3(256), 0, stream>>>(a);
  }

  // ---- context projections + s0 ----
  {
    Ctx16 a = {};
    for (int i = 0; i < 5; ++i) {
      a.W[i] = H16 + (size_t)(6 + i) * 1024000;
      a.mode[i] = (i == 4) ? 2 : 0;
    }
    a.out[0] = cCr; a.out[1] = cCz; a.out[2] = cC; a.out[3] = cCo; a.out[4] = nullptr;
    a.x = hbk; a.hbk2 = hbk2; a.srm0 = Srm16;
    ctx_mv16<<<dim3(250, 1, 5), dim3(256), 0, stream>>>(a);
  }

  // ---- decoder recurrence: ONE persistent launch, 23 steps ----
  {
    Seq a = {};
    a.steps = T_ - 1;
    a.Xr = YPr; a.Xz = YPz; a.Xc = YPc;
    a.Ur = decUr16; a.Uz = decUz16; a.U = decU16;
    a.cr = cCr; a.cz = cCz; a.cc = cC;
    a.br = dec_br; a.bz = dec_bz; a.bb = dec_b;
    a.h = hbk2; a.rh = rhbk;
    a.srm = Srm16; a.bar = barD;
    gru_seq<<<dim3(250), dim3(256), 0, stream>>>(a);
  }

  // ---- maxout GEMM: t = Srm@U_o^T + YV + cCo -> Tmax bf16 [768][512] ----
  {
    MG g = {};
    g.A[0] = Srm16; g.Bw[0] = Uo16;
    g.M = T_ * B_; g.N = M2_; g.Kp = HP_; g.ldc = 0; g.mode = 1;
    g.e1 = YV; g.e2 = cCo; g.tmax = Tmax;
    mgemm<<<dim3(8, 6, 1), dim3(256), 0, stream>>>(g);
  }

  // ---- logits = Tmax @ W_o^T -> out[b][t][v] ----
  {
    MG g = {};
    g.A[0] = Tmax; g.Bw[0] = Wo16; g.C[0] = out;
    g.M = T_ * B_; g.N = V_; g.Kp = KW_; g.ldc = V_; g.mode = 2;
    mgemm<<<dim3(235, 6, 1), dim3(256), 0, stream>>>(g);
  }
}

// Round 3
// 2148.344 us; speedup vs baseline: 3.2048x; 2.3518x over previous
//
#include <hip/hip_runtime.h>
#include <math.h>

typedef unsigned short ushort;
typedef unsigned int uint;
typedef __attribute__((ext_vector_type(8))) short bf16x8;
typedef __attribute__((ext_vector_type(4))) float f32x4;

#define B_  32
#define S_  24
#define T_  24
#define E_  620
#define EP_ 640
#define H_  1000
#define HP_ 1024
#define V_  30000
#define M2_ 1000
#define KW_ 512

__device__ __forceinline__ ushort f2bf(float f) {
  uint u = __float_as_uint(f);
  u += 0x7FFFu + ((u >> 16) & 1u);
  return (ushort)(u >> 16);
}
__device__ __forceinline__ float bf2f(ushort s) {
  return __uint_as_float(((uint)s) << 16);
}

// write-through store: lands at the device coherence point (L3), leaves no
// dirty L2 line -> no buffer_wbl2 needed at the grid barrier, no
// false-sharing writeback storms from partial-line writes.
__device__ __forceinline__ void st_wt(float* p, float v) {
  asm volatile("global_store_dword %0, %1, off sc0 sc1" :: "v"(p), "v"(v) : "memory");
}

// ---------------------------------------------------------------------------
// weight conversion: fp32 [N][K] -> bf16 [N][Kp] zero-padded
// ---------------------------------------------------------------------------
struct ConvJobs {
  const float* in[19];
  ushort* out[19];
  int K[19], Kp[19];
};
__global__ __launch_bounds__(256) void conv_small(ConvJobs a) {
  int j = blockIdx.y, row = blockIdx.x;
  const float* ip = a.in[j] + (size_t)row * a.K[j];
  ushort* op = a.out[j] + (size_t)row * a.Kp[j];
  for (int k = threadIdx.x; k < a.Kp[j]; k += 256)
    op[k] = (k < a.K[j]) ? f2bf(ip[k]) : (ushort)0;
}

__global__ __launch_bounds__(256) void conv_wo(const float* __restrict__ in,
                                               ushort* __restrict__ out) {
  int row = blockIdx.x;
  const float* ip = in + (size_t)row * 500;
  ushort* op = out + (size_t)row * 512;
  int k = threadIdx.x;
  op[k] = (k < 500) ? f2bf(ip[k]) : (ushort)0;
  k += 256;
  op[k] = (k < 500) ? f2bf(ip[k]) : (ushort)0;
}

// ---------------------------------------------------------------------------
// embedding gather -> bf16, K padded 620->640
// ---------------------------------------------------------------------------
__global__ __launch_bounds__(256) void gather16(
    const int* __restrict__ src, const int* __restrict__ tgt,
    const float* __restrict__ semb, const float* __restrict__ temb,
    ushort* __restrict__ XE, ushort* __restrict__ YE) {
  int row = blockIdx.x;
  int isT = row >= S_ * B_;
  int r = isT ? row - S_ * B_ : row;
  int st = r >> 5, b = r & 31;
  int tok = isT ? tgt[b * T_ + st] : src[b * S_ + st];
  const float* e = (isT ? temb : semb) + (size_t)tok * E_;
  ushort* o = (isT ? YE : XE) + (size_t)r * EP_;
  for (int k = threadIdx.x; k < EP_; k += 256)
    o[k] = (k < E_) ? f2bf(e[k]) : (ushort)0;
}

// ---------------------------------------------------------------------------
// bf16 MFMA GEMM: C = A @ Bw^T. A [M][Kp] bf16, Bw [N][Kp] bf16.
// 128x128 tile, 4 waves, each 64x64 (4x4 frags of 16x16x32).
// Register-staged double buffer.
// mode 0: fp32 store C[row][col] (ldc)
// mode 1: maxout: v = acc+e1[row][col]+e2[row&31][col]; pair-max -> bf16 tmax
// mode 2: scatter: row=t*32+b -> C[(b*T+t)*ldc + col]
// ---------------------------------------------------------------------------
struct MG {
  const ushort* A[8];
  const ushort* Bw[8];
  float* C[8];
  int M, N, Kp, ldc;
  int mode;
  const float* e1;
  const float* e2;
  ushort* tmax;
};

__global__ __launch_bounds__(256) void mgemm(MG g) {
  __shared__ ushort As[128 * 40];
  __shared__ ushort Bs[128 * 40];
  const int z = blockIdx.z;
  const ushort* __restrict__ A = g.A[z];
  const ushort* __restrict__ Bw = g.Bw[z];
  const int tid = threadIdx.x;
  const int wave = tid >> 6, lane = tid & 63;
  const int lm = lane & 15, kq = lane >> 4;
  const int wm = (wave >> 1) * 64, wn = (wave & 1) * 64;
  const int m0 = blockIdx.y * 128, n0 = blockIdx.x * 128;
  const int Kp = g.Kp;

  f32x4 acc[4][4];
#pragma unroll
  for (int i = 0; i < 4; ++i)
#pragma unroll
    for (int j = 0; j < 4; ++j) acc[i][j] = (f32x4){0.f, 0.f, 0.f, 0.f};

  const int row_s = tid >> 2, seg = tid & 3;

  uint4 va[2], vb[2];
  auto ld = [&](int k0) {
#pragma unroll
    for (int p = 0; p < 2; ++p) {
      int gm = m0 + row_s + p * 64;
      va[p] = make_uint4(0, 0, 0, 0);
      if (gm < g.M) va[p] = *(const uint4*)(A + (size_t)gm * Kp + k0 + seg * 8);
      int gn = n0 + row_s + p * 64;
      vb[p] = make_uint4(0, 0, 0, 0);
      if (gn < g.N) vb[p] = *(const uint4*)(Bw + (size_t)gn * Kp + k0 + seg * 8);
    }
  };

  ld(0);
  for (int k0 = 0; k0 < Kp; k0 += 32) {
#pragma unroll
    for (int p = 0; p < 2; ++p) {
      int row = row_s + p * 64;
      *(uint4*)&As[row * 40 + seg * 8] = va[p];
      *(uint4*)&Bs[row * 40 + seg * 8] = vb[p];
    }
    __syncthreads();
    if (k0 + 32 < Kp) ld(k0 + 32);  // issue next-tile loads under the MFMAs
    bf16x8 af[4], bfr[4];
#pragma unroll
    for (int i = 0; i < 4; ++i)
      af[i] = *(const bf16x8*)&As[(wm + i * 16 + lm) * 40 + kq * 8];
#pragma unroll
    for (int j = 0; j < 4; ++j)
      bfr[j] = *(const bf16x8*)&Bs[(wn + j * 16 + lm) * 40 + kq * 8];
#pragma unroll
    for (int i = 0; i < 4; ++i)
#pragma unroll
      for (int j = 0; j < 4; ++j)
        acc[i][j] = __builtin_amdgcn_mfma_f32_16x16x32_bf16(af[i], bfr[j], acc[i][j], 0, 0, 0);
    __syncthreads();
  }

#pragma unroll
  for (int i = 0; i < 4; ++i) {
    int grow = m0 + wm + i * 16 + kq * 4;
#pragma unroll
    for (int j = 0; j < 4; ++j) {
      int gcol = n0 + wn + j * 16 + lm;
#pragma unroll
      for (int r = 0; r < 4; ++r) {
        int row = grow + r;
        float v = acc[i][j][r];
        if (g.mode == 0) {
          if (row < g.M && gcol < g.N) g.C[z][(size_t)row * g.ldc + gcol] = v;
        } else if (g.mode == 1) {
          float vv = v;
          if (row < g.M && gcol < g.N)
            vv += g.e1[(size_t)row * M2_ + gcol] + g.e2[(size_t)(row & 31) * M2_ + gcol];
          float other = __shfl_xor(vv, 1);
          if ((lane & 1) == 0 && row < g.M && gcol < g.N)
            g.tmax[(size_t)row * KW_ + (gcol >> 1)] = f2bf(fmaxf(vv, other));
        } else {
          if (row < g.M && gcol < g.N) {
            int t = row >> 5, b = row & 31;
            g.C[z][((size_t)b * T_ + t) * (size_t)g.ldc + gcol] = v;
          }
        }
      }
    }
  }
}

// ---------------------------------------------------------------------------
// Tree grid barrier. No release fence (data goes out via write-through sc0/sc1
// stores, drained by per-wave vmcnt(0) before arrival). Arrival: 16 leaf
// counters on separate 128B lines -> root -> broadcast epoch flag. Spin on the
// flag with RELAXED loads. One acquire fence (cache invalidate; caches are
// clean so it is cheap) after exit so ordinary loads refetch from L3.
// Layout at base (uint*): leaf[lf]=base+lf*32, root=base+16*32, flag=base+17*32.
// ---------------------------------------------------------------------------
__device__ __forceinline__ void gbar(uint* base, int nb, uint& phase) {
  asm volatile("s_waitcnt vmcnt(0)" ::: "memory");  // every wave drains its wt stores
  __syncthreads();
  ++phase;
  if (threadIdx.x == 0) {
    int lf = blockIdx.x & 15;
    uint cnt = (uint)((nb - lf + 15) >> 4);  // #blocks with blockIdx%16==lf
    uint* leaf = base + lf * 32;
    uint* root = base + 16 * 32;
    uint* flag = base + 17 * 32;
    uint old = __hip_atomic_fetch_add(leaf, 1u, __ATOMIC_RELAXED, __HIP_MEMORY_SCOPE_AGENT);
    if (old + 1 == cnt * phase) {  // last arriver in this leaf
      uint r = __hip_atomic_fetch_add(root, 1u, __ATOMIC_RELAXED, __HIP_MEMORY_SCOPE_AGENT);
      if (r + 1 == 16u * phase)    // last leaf -> broadcast
        __hip_atomic_store(flag, phase, __ATOMIC_RELAXED, __HIP_MEMORY_SCOPE_AGENT);
    }
    while (__hip_atomic_load(flag, __ATOMIC_RELAXED, __HIP_MEMORY_SCOPE_AGENT) < phase)
      __builtin_amdgcn_s_sleep(2);
  }
  __syncthreads();
  __builtin_amdgcn_fence(__ATOMIC_ACQUIRE, "agent");  // invalidate stale L1/L2 lines
}

// ---------------------------------------------------------------------------
// Persistent GRU sequence kernel. ONE launch per recurrence.
// LDS-resident per-step operands (weights, X, ctx, bias, z). Cross-block
// exchange (h, rh) via write-through stores + post-barrier L3 reads.
// ---------------------------------------------------------------------------
struct Seq {
  int steps;
  const float* Xr; const float* Xz; const float* Xc;  // [steps][32][1000]
  const ushort *Ur, *Uz, *U;                          // bf16 [1000][1024]
  const float *cr, *cz, *cc;                          // nullable ctx adds
  const float *br, *bz, *bb;
  float* h;          // state [32][1024] fp32 (padding stays 0)
  float* rh;         // r*h scratch [32][1024]
  ushort* srm;       // if non-null: bf16 state log at (t+1)*32*1024
  uint* bar;
};

__global__ __launch_bounds__(256) void gru_seq(Seq a) {
  __shared__ ushort Wlds[3 * 4 * 1024];   // [mat][row 0..3][k 0..1023]
  __shared__ float  Xlds[24 * 384];       // [t][mat][eb*4+ej]
  __shared__ float  redA[4][4][2][32];
  __shared__ float  redB[4][4][32];
  __shared__ float  Clds[3][128];         // ctx adds [mat][eb*4+ej]
  __shared__ float  blds[3][4];           // biases   [mat][ej]
  __shared__ float  zlds[128];            // z gate   [eb*4+ej] (block-local)

  const int tid = threadIdx.x;
  const int w = tid >> 6, lane = tid & 63;
  const int b = lane & 31, kh = lane >> 5;
  const int j0 = blockIdx.x * 4;
  const int kbase = w * 256 + kh * 128;
  const int nb = gridDim.x;
  uint phase = 0;

  // epilogue thread mapping
  const int eb = tid & 31;
  const int eg = (tid >> 5) & 1;   // phase A: 0 -> r-gate, 1 -> z-gate
  const int ejA = tid >> 6;        // phase A output col within block
  const int exA = eb * 4 + ejA;
  const int ejB = (tid >> 5) & 3;  // phase B (tid<128) col within block
  const int exB = eb * 4 + ejB;

  // ---- one-time preload: weights -> LDS (bf16) ----
  {
    const ushort* Ws[3] = {a.Ur, a.Uz, a.U};
    for (int q = tid; q < 3 * 4 * 128; q += 256) {
      int mat = q >> 9;
      int rem = q & 511;
      int row = rem >> 7;
      int k8 = (rem & 127) << 3;
      *(bf16x8*)&Wlds[mat * 4096 + row * 1024 + k8] =
          *(const bf16x8*)(Ws[mat] + (size_t)(j0 + row) * HP_ + k8);
    }
  }
  // ---- one-time preload: X projections, all steps ----
  for (int q = tid; q < a.steps * 384; q += 256) {
    int t = q / 384;
    int rem = q - t * 384;
    int mat = rem >> 7;
    int r2 = rem & 127;
    const float* Xs = (mat == 0 ? a.Xr : mat == 1 ? a.Xz : a.Xc) + t * 32000;
    Xlds[q] = Xs[(r2 >> 2) * H_ + j0 + (r2 & 3)];
  }
  // ---- one-time preload: ctx adds + biases ----
  if (a.cr) {
    const float* Cs[3] = {a.cr, a.cz, a.cc};
    for (int q = tid; q < 3 * 128; q += 256) {
      int mat = q >> 7, r2 = q & 127;
      Clds[mat][r2] = Cs[mat][(r2 >> 2) * H_ + j0 + (r2 & 3)];
    }
  } else {
    for (int q = tid; q < 3 * 128; q += 256) Clds[q >> 7][q & 127] = 0.f;
  }
  if (tid < 12) {
    const float* bs[3] = {a.br, a.bz, a.bb};
    blds[tid >> 2][tid & 3] = bs[tid >> 2][j0 + (tid & 3)];
  }
  __syncthreads();

  for (int t = 0; t < a.steps; ++t) {
    // ---- phase A: pre_r = h@Ur^T, pre_z = h@Uz^T -> rh, z ----
    {
      float xA = Xlds[t * 384 + eg * 128 + exA];
      const float4* h4 = (const float4*)(a.h + b * HP_ + kbase);
      float accr[4] = {0.f, 0.f, 0.f, 0.f}, accz[4] = {0.f, 0.f, 0.f, 0.f};
#pragma unroll
      for (int i = 0; i < 16; ++i) {
        float4 ha = h4[2 * i], hb2 = h4[2 * i + 1];
        float hv[8] = {ha.x, ha.y, ha.z, ha.w, hb2.x, hb2.y, hb2.z, hb2.w};
        int k = kbase + i * 8;
#pragma unroll
        for (int j = 0; j < 4; ++j) {
          bf16x8 u = *(const bf16x8*)&Wlds[j * 1024 + k];
          bf16x8 v = *(const bf16x8*)&Wlds[4096 + j * 1024 + k];
#pragma unroll
          for (int e = 0; e < 8; ++e) {
            accr[j] = fmaf(hv[e], bf2f((ushort)u[e]), accr[j]);
            accz[j] = fmaf(hv[e], bf2f((ushort)v[e]), accz[j]);
          }
        }
      }
#pragma unroll
      for (int j = 0; j < 4; ++j) {
        float pr = accr[j] + __shfl_xor(accr[j], 32);
        float pz = accz[j] + __shfl_xor(accz[j], 32);
        if (lane < 32) {
          redA[w][j][0][b] = pr;
          redA[w][j][1][b] = pz;
        }
      }
      __syncthreads();
      {
        float s = redA[0][ejA][eg][eb] + redA[1][ejA][eg][eb] +
                  redA[2][ejA][eg][eb] + redA[3][ejA][eg][eb];
        int j = j0 + ejA;
        float pre = s + xA + blds[eg][ejA] + Clds[eg][exA];
        float sg = 1.f / (1.f + expf(-pre));
        if (eg == 0) {
          st_wt(&a.rh[eb * HP_ + j], sg * a.h[eb * HP_ + j]);
        } else {
          zlds[exA] = sg;
        }
      }
    }
    gbar(a.bar, nb, phase);

    // ---- phase B: cand = tanh(rh@U^T + Xc + cc + b); h = (1-z)h + z*cand ----
    {
      float xB = (tid < 128) ? Xlds[t * 384 + 256 + exB] : 0.f;
      const float4* h4 = (const float4*)(a.rh + b * HP_ + kbase);
      float acc[4] = {0.f, 0.f, 0.f, 0.f};
#pragma unroll
      for (int i = 0; i < 16; ++i) {
        float4 ha = h4[2 * i], hb2 = h4[2 * i + 1];
        float hv[8] = {ha.x, ha.y, ha.z, ha.w, hb2.x, hb2.y, hb2.z, hb2.w};
        int k = kbase + i * 8;
#pragma unroll
        for (int j = 0; j < 4; ++j) {
          bf16x8 u = *(const bf16x8*)&Wlds[8192 + j * 1024 + k];
#pragma unroll
          for (int e = 0; e < 8; ++e)
            acc[j] = fmaf(hv[e], bf2f((ushort)u[e]), acc[j]);
        }
      }
#pragma unroll
      for (int j = 0; j < 4; ++j) {
        float p = acc[j] + __shfl_xor(acc[j], 32);
        if (lane < 32) redB[w][j][b] = p;
      }
      __syncthreads();
      if (tid < 128) {
        float s = redB[0][ejB][eb] + redB[1][ejB][eb] +
                  redB[2][ejB][eb] + redB[3][ejB][eb];
        int j = j0 + ejB;
        float cand = tanhf(s + xB + blds[2][ejB] + Clds[2][exB]);
        float z = zlds[exB];
        float old = a.h[eb * HP_ + j];
        float nv = (1.f - z) * old + z * cand;
        st_wt(&a.h[eb * HP_ + j], nv);
        if (a.srm) a.srm[(size_t)(t + 1) * B_ * HP_ + eb * HP_ + j] = f2bf(nv);
      }
    }
    if (t != a.steps - 1) gbar(a.bar, nb, phase);
    // final step: kernel-end flush handles visibility for the next launch
  }
}

// ---------------------------------------------------------------------------
// context projections + s0 (bf16 weights)
// ---------------------------------------------------------------------------
struct Ctx16 {
  const ushort* W[5];
  float* out[5];
  int mode[5];
  const float* x;
  float* hbk2;
  ushort* srm0;
};

__global__ __launch_bounds__(256) void ctx_mv16(Ctx16 a) {
  __shared__ float red[4][4][32];
  const int z = blockIdx.z;
  const ushort* __restrict__ W = a.W[z];
  const float* __restrict__ x = a.x;
  const int tid = threadIdx.x;
  const int w = tid >> 6, lane = tid & 63;
  const int b = lane & 31, kh = lane >> 5;
  const int j0 = blockIdx.x * 4;
  const int kbase = w * 256 + kh * 128;
  const float4* h4 = (const float4*)(x + b * HP_ + kbase);
  float acc[4] = {0.f, 0.f, 0.f, 0.f};
#pragma unroll
  for (int i = 0; i < 16; ++i) {
    float4 ha = h4[2 * i], hb = h4[2 * i + 1];
    float hv[8] = {ha.x, ha.y, ha.z, ha.w, hb.x, hb.y, hb.z, hb.w};
    int k = kbase + i * 8;
#pragma unroll
    for (int j = 0; j < 4; ++j) {
      bf16x8 u = *(const bf16x8*)(W + (size_t)(j0 + j) * HP_ + k);
#pragma unroll
      for (int e = 0; e < 8; ++e)
        acc[j] = fmaf(hv[e], bf2f((ushort)u[e]), acc[j]);
    }
  }
  float p[4];
#pragma unroll
  for (int j = 0; j < 4; ++j) p[j] = acc[j] + __shfl_xor(acc[j], 32);
  if (lane < 32) {
#pragma unroll
    for (int j = 0; j < 4; ++j) red[w][j][b] = p[j];
  }
  __syncthreads();
  if (tid < 128) {
    int eb = tid & 31, ej = tid >> 5;
    float s = red[0][ej][eb] + red[1][ej][eb] + red[2][ej][eb] + red[3][ej][eb];
    int j = j0 + ej;
    if (a.mode[z] == 0) {
      a.out[z][eb * H_ + j] = s;
    } else {
      float v = tanhf(s);
      a.hbk2[eb * HP_ + j] = v;
      a.srm0[eb * HP_ + j] = f2bf(v);
    }
  }
}

// ---------------------------------------------------------------------------
// Host
// ---------------------------------------------------------------------------
extern "C" void kernel_launch(void* const* d_in, const int* in_sizes, int n_in,
                              void* d_out, int out_size, void* d_ws, size_t ws_size,
                              hipStream_t stream) {
  const int*   src     = (const int*)d_in[0];
  const int*   tgt     = (const int*)d_in[1];
  const float* src_emb = (const float*)d_in[3];
  const float* tgt_emb = (const float*)d_in[4];
  const float* enc_W   = (const float*)d_in[5];
  const float* enc_Wz  = (const float*)d_in[6];
  const float* enc_Wr  = (const float*)d_in[7];
  const float* enc_U   = (const float*)d_in[8];
  const float* enc_Uz  = (const float*)d_in[9];
  const float* enc_Ur  = (const float*)d_in[10];
  const float* enc_b   = (const float*)d_in[11];
  const float* enc_bz  = (const float*)d_in[12];
  const float* enc_br  = (const float*)d_in[13];
  const float* dec_W   = (const float*)d_in[14];
  const float* dec_Wz  = (const float*)d_in[15];
  const float* dec_Wr  = (const float*)d_in[16];
  const float* dec_U   = (const float*)d_in[17];
  const float* dec_Uz  = (const float*)d_in[18];
  const float* dec_Ur  = (const float*)d_in[19];
  const float* dec_C   = (const float*)d_in[20];
  const float* dec_Cz  = (const float*)d_in[21];
  const float* dec_Cr  = (const float*)d_in[22];
  const float* dec_b   = (const float*)d_in[23];
  const float* dec_bz  = (const float*)d_in[24];
  const float* dec_br  = (const float*)d_in[25];
  const float* W_s     = (const float*)d_in[26];
  const float* U_o     = (const float*)d_in[27];
  const float* V_o     = (const float*)d_in[28];
  const float* C_o     = (const float*)d_in[29];
  const float* W_o     = (const float*)d_in[30];
  float* out = (float*)d_out;
  char* wsb = (char*)d_ws;
  (void)in_sizes; (void)n_in; (void)out_size; (void)ws_size;

  // byte-offset workspace layout
  float*  hbk   = (float*)(wsb + 0);         // 32x1024
  float*  rhbk  = (float*)(wsb + 131072);
  float*  hbk2  = (float*)(wsb + 262144);
  ushort* Srm16 = (ushort*)(wsb + 393216);   // 768x1024 bf16
  ushort* Tmax  = (ushort*)(wsb + 1966080);  // 768x512 bf16
  // zero block ends at 2752512
  float*  cCr   = (float*)(wsb + 2880512);
  float*  cCz   = (float*)(wsb + 3008512);
  float*  cC    = (float*)(wsb + 3136512);
  float*  cCo   = (float*)(wsb + 3264512);
  float*  YV    = (float*)(wsb + 3392512);   // 768x1000
  float*  XPr   = (float*)(wsb + 6464512);
  float*  XPz   = (float*)(wsb + 9536512);
  float*  XPc   = (float*)(wsb + 12608512);
  float*  YPr   = (float*)(wsb + 15680512);
  float*  YPz   = (float*)(wsb + 18752512);
  float*  YPc   = (float*)(wsb + 21824512);
  ushort* XE16  = (ushort*)(wsb + 24896512); // 768x640 bf16
  ushort* YE16  = (ushort*)(wsb + 25879552);
  ushort* H16   = (ushort*)(wsb + 26862592); // 12 x 1000x1024 bf16
  ushort* E16   = (ushort*)(wsb + 51438592); // 7 x 1000x640 bf16
  ushort* Wo16  = (ushort*)(wsb + 60398592); // 30000x512 bf16

  // barrier regions: first 8KB of out (16 leaf lines + root + flag each),
  // fully overwritten by the final logits GEMM
  uint* barE = (uint*)((char*)d_out + 0);
  uint* barD = (uint*)((char*)d_out + 4096);

  // zero: state buffers + Srm16 pads + Tmax pads; barrier counters
  hipMemsetAsync(wsb, 0, 2752512, stream);
  hipMemsetAsync(d_out, 0, 8192, stream);

  // ---- weight conversions (per call; ws is re-poisoned each call) ----
  {
    ConvJobs a = {};
    const float* hin[12] = {enc_Ur, enc_Uz, enc_U, dec_Ur, dec_Uz, dec_U,
                            dec_Cr, dec_Cz, dec_C, C_o, W_s, U_o};
    const float* ein[7]  = {enc_Wr, enc_Wz, enc_W, dec_Wr, dec_Wz, dec_W, V_o};
    for (int i = 0; i < 12; ++i) {
      a.in[i] = hin[i]; a.out[i] = H16 + (size_t)i * 1000 * HP_;
      a.K[i] = H_; a.Kp[i] = HP_;
    }
    for (int i = 0; i < 7; ++i) {
      a.in[12 + i] = ein[i]; a.out[12 + i] = E16 + (size_t)i * 1000 * EP_;
      a.K[12 + i] = E_; a.Kp[12 + i] = EP_;
    }
    conv_small<<<dim3(1000, 19), dim3(256), 0, stream>>>(a);
  }
  conv_wo<<<dim3(V_), dim3(256), 0, stream>>>(W_o, Wo16);

  gather16<<<dim3(2 * S_ * B_), dim3(256), 0, stream>>>(src, tgt, src_emb, tgt_emb, XE16, YE16);

  // ---- batched input projections (MFMA): M=768 N=1000 Kp=640 ----
  {
    MG g = {};
    const ushort* As[7] = {XE16, XE16, XE16, YE16, YE16, YE16, YE16};
    float* Cs[7] = {XPr, XPz, XPc, YPr, YPz, YPc, YV};
    for (int i = 0; i < 7; ++i) {
      g.A[i] = As[i]; g.Bw[i] = E16 + (size_t)i * 1000 * EP_; g.C[i] = Cs[i];
    }
    g.M = S_ * B_; g.N = H_; g.Kp = EP_; g.ldc = H_; g.mode = 0;
    mgemm<<<dim3(8, 6, 7), dim3(256), 0, stream>>>(g);
  }

  const ushort* encUr16 = H16 + 0 * 1024000;
  const ushort* encUz16 = H16 + 1 * 1024000;
  const ushort* encU16  = H16 + 2 * 1024000;
  const ushort* decUr16 = H16 + 3 * 1024000;
  const ushort* decUz16 = H16 + 4 * 1024000;
  const ushort* decU16  = H16 + 5 * 1024000;
  const ushort* Uo16    = H16 + 11 * 1024000;

  // ---- encoder recurrence: ONE persistent launch, 24 steps ----
  {
    Seq a = {};
    a.steps = S_;
    a.Xr = XPr; a.Xz = XPz; a.Xc = XPc;
    a.Ur = encUr16; a.Uz = encUz16; a.U = encU16;
    a.cr = nullptr; a.cz = nullptr; a.cc = nullptr;
    a.br = enc_br; a.bz = enc_bz; a.bb = enc_b;
    a.h = hbk; a.rh = rhbk;
    a.srm = nullptr; a.bar = barE;
    gru_seq<<<dim3(250), dim3(256), 0, stream>>>(a);
  }

  // ---- context projections + s0 ----
  {
    Ctx16 a = {};
    for (int i = 0; i < 5; ++i) {
      a.W[i] = H16 + (size_t)(6 + i) * 1024000;
      a.mode[i] = (i == 4) ? 2 : 0;
    }
    a.out[0] = cCr; a.out[1] = cCz; a.out[2] = cC; a.out[3] = cCo; a.out[4] = nullptr;
    a.x = hbk; a.hbk2 = hbk2; a.srm0 = Srm16;
    ctx_mv16<<<dim3(250, 1, 5), dim3(256), 0, stream>>>(a);
  }

  // ---- decoder recurrence: ONE persistent launch, 23 steps ----
  {
    Seq a = {};
    a.steps = T_ - 1;
    a.Xr = YPr; a.Xz = YPz; a.Xc = YPc;
    a.Ur = decUr16; a.Uz = decUz16; a.U = decU16;
    a.cr = cCr; a.cz = cCz; a.cc = cC;
    a.br = dec_br; a.bz = dec_bz; a.bb = dec_b;
    a.h = hbk2; a.rh = rhbk;
    a.srm = Srm16; a.bar = barD;
    gru_seq<<<dim3(250), dim3(256), 0, stream>>>(a);
  }

  // ---- maxout GEMM: t = Srm@U_o^T + YV + cCo -> Tmax bf16 [768][512] ----
  {
    MG g = {};
    g.A[0] = Srm16; g.Bw[0] = Uo16;
    g.M = T_ * B_; g.N = M2_; g.Kp = HP_; g.ldc = 0; g.mode = 1;
    g.e1 = YV; g.e2 = cCo; g.tmax = Tmax;
    mgemm<<<dim3(8, 6, 1), dim3(256), 0, stream>>>(g);
  }

  // ---- logits = Tmax @ W_o^T -> out[b][t][v] ----
  {
    MG g = {};
    g.A[0] = Tmax; g.Bw[0] = Wo16; g.C[0] = out;
    g.M = T_ * B_; g.N = V_; g.Kp = KW_; g.ldc = V_; g.mode = 2;
    mgemm<<<dim3(235, 6, 1), dim3(256), 0, stream>>>(g);
  }
}

// Round 5
// 1157.676 us; speedup vs baseline: 5.9472x; 1.8557x over previous
//
#include <hip/hip_runtime.h>
#include <math.h>

typedef unsigned short ushort;
typedef unsigned int uint;
typedef __attribute__((ext_vector_type(8))) short bf16x8;
typedef __attribute__((ext_vector_type(4))) float f32x4;

#define B_  32
#define S_  24
#define T_  24
#define E_  620
#define EP_ 640
#define H_  1000
#define HP_ 1024
#define V_  30000
#define M2_ 1000
#define KW_ 512

__device__ __forceinline__ ushort f2bf(float f) {
  uint u = __float_as_uint(f);
  u += 0x7FFFu + ((u >> 16) & 1u);
  return (ushort)(u >> 16);
}
__device__ __forceinline__ float bf2f(ushort s) {
  return __uint_as_float(((uint)s) << 16);
}

// coherent (L3 coherence-point) access helpers: no dirty L2 lines, no stale
// L2 reads -> the grid barrier needs NO cache fences at all.
// NOTE: asm 'v' constraints need ext_vector types (f32x4), not HIP float4
// structs (indirect operands are rejected by the backend).
__device__ __forceinline__ void st_wt4(float* p, f32x4 v) {
  asm volatile("global_store_dwordx4 %0, %1, off sc0 sc1" :: "v"(p), "v"(v) : "memory");
}
__device__ __forceinline__ float ld_cv(const float* p) {
  float v;
  asm volatile("global_load_dword %0, %1, off sc0 sc1" : "=v"(v) : "v"(p) : "memory");
  asm volatile("s_waitcnt vmcnt(0)" ::: "memory");
  __builtin_amdgcn_sched_barrier(0);
  return v;
}

#define LDCV4(dst, ptr) \
  asm volatile("global_load_dwordx4 %0, %1, off sc0 sc1" : "=v"(dst) : "v"(ptr) : "memory");
#define DECLC(p) f32x4 p##0, p##1, p##2, p##3, p##4, p##5, p##6, p##7;
#define LOADCQ(p, bp) \
  LDCV4(p##0, (bp) + 0 * HP_) LDCV4(p##1, (bp) + 1 * HP_) \
  LDCV4(p##2, (bp) + 2 * HP_) LDCV4(p##3, (bp) + 3 * HP_) \
  LDCV4(p##4, (bp) + 4 * HP_) LDCV4(p##5, (bp) + 5 * HP_) \
  LDCV4(p##6, (bp) + 6 * HP_) LDCV4(p##7, (bp) + 7 * HP_)
#define VWAIT(n) \
  asm volatile("s_waitcnt vmcnt(" #n ")" ::: "memory"); \
  __builtin_amdgcn_sched_barrier(0);

// ---------------------------------------------------------------------------
// weight conversion: fp32 [N][K] -> bf16 [N][Kp] zero-padded
// ---------------------------------------------------------------------------
struct ConvJobs {
  const float* in[19];
  ushort* out[19];
  int K[19], Kp[19];
};
__global__ __launch_bounds__(256) void conv_small(ConvJobs a) {
  int j = blockIdx.y, row = blockIdx.x;
  const float* ip = a.in[j] + (size_t)row * a.K[j];
  ushort* op = a.out[j] + (size_t)row * a.Kp[j];
  for (int k = threadIdx.x; k < a.Kp[j]; k += 256)
    op[k] = (k < a.K[j]) ? f2bf(ip[k]) : (ushort)0;
}

__global__ __launch_bounds__(256) void conv_wo(const float* __restrict__ in,
                                               ushort* __restrict__ out) {
  int row = blockIdx.x;
  const float* ip = in + (size_t)row * 500;
  ushort* op = out + (size_t)row * 512;
  int k = threadIdx.x;
  op[k] = (k < 500) ? f2bf(ip[k]) : (ushort)0;
  k += 256;
  op[k] = (k < 500) ? f2bf(ip[k]) : (ushort)0;
}

// ---------------------------------------------------------------------------
// embedding gather -> bf16, K padded 620->640
// ---------------------------------------------------------------------------
__global__ __launch_bounds__(256) void gather16(
    const int* __restrict__ src, const int* __restrict__ tgt,
    const float* __restrict__ semb, const float* __restrict__ temb,
    ushort* __restrict__ XE, ushort* __restrict__ YE) {
  int row = blockIdx.x;
  int isT = row >= S_ * B_;
  int r = isT ? row - S_ * B_ : row;
  int st = r >> 5, b = r & 31;
  int tok = isT ? tgt[b * T_ + st] : src[b * S_ + st];
  const float* e = (isT ? temb : semb) + (size_t)tok * E_;
  ushort* o = (isT ? YE : XE) + (size_t)r * EP_;
  for (int k = threadIdx.x; k < EP_; k += 256)
    o[k] = (k < E_) ? f2bf(e[k]) : (ushort)0;
}

// ---------------------------------------------------------------------------
// bf16 MFMA GEMM: C = A @ Bw^T (unchanged)
// ---------------------------------------------------------------------------
struct MG {
  const ushort* A[8];
  const ushort* Bw[8];
  float* C[8];
  int M, N, Kp, ldc;
  int mode;
  const float* e1;
  const float* e2;
  ushort* tmax;
};

__global__ __launch_bounds__(256) void mgemm(MG g) {
  __shared__ ushort As[128 * 40];
  __shared__ ushort Bs[128 * 40];
  const int z = blockIdx.z;
  const ushort* __restrict__ A = g.A[z];
  const ushort* __restrict__ Bw = g.Bw[z];
  const int tid = threadIdx.x;
  const int wave = tid >> 6, lane = tid & 63;
  const int lm = lane & 15, kq = lane >> 4;
  const int wm = (wave >> 1) * 64, wn = (wave & 1) * 64;
  const int m0 = blockIdx.y * 128, n0 = blockIdx.x * 128;
  const int Kp = g.Kp;

  f32x4 acc[4][4];
#pragma unroll
  for (int i = 0; i < 4; ++i)
#pragma unroll
    for (int j = 0; j < 4; ++j) acc[i][j] = (f32x4){0.f, 0.f, 0.f, 0.f};

  const int row_s = tid >> 2, seg = tid & 3;

  uint4 va[2], vb[2];
  auto ld = [&](int k0) {
#pragma unroll
    for (int p = 0; p < 2; ++p) {
      int gm = m0 + row_s + p * 64;
      va[p] = make_uint4(0, 0, 0, 0);
      if (gm < g.M) va[p] = *(const uint4*)(A + (size_t)gm * Kp + k0 + seg * 8);
      int gn = n0 + row_s + p * 64;
      vb[p] = make_uint4(0, 0, 0, 0);
      if (gn < g.N) vb[p] = *(const uint4*)(Bw + (size_t)gn * Kp + k0 + seg * 8);
    }
  };

  ld(0);
  for (int k0 = 0; k0 < Kp; k0 += 32) {
#pragma unroll
    for (int p = 0; p < 2; ++p) {
      int row = row_s + p * 64;
      *(uint4*)&As[row * 40 + seg * 8] = va[p];
      *(uint4*)&Bs[row * 40 + seg * 8] = vb[p];
    }
    __syncthreads();
    if (k0 + 32 < Kp) ld(k0 + 32);
    bf16x8 af[4], bfr[4];
#pragma unroll
    for (int i = 0; i < 4; ++i)
      af[i] = *(const bf16x8*)&As[(wm + i * 16 + lm) * 40 + kq * 8];
#pragma unroll
    for (int j = 0; j < 4; ++j)
      bfr[j] = *(const bf16x8*)&Bs[(wn + j * 16 + lm) * 40 + kq * 8];
#pragma unroll
    for (int i = 0; i < 4; ++i)
#pragma unroll
      for (int j = 0; j < 4; ++j)
        acc[i][j] = __builtin_amdgcn_mfma_f32_16x16x32_bf16(af[i], bfr[j], acc[i][j], 0, 0, 0);
    __syncthreads();
  }

#pragma unroll
  for (int i = 0; i < 4; ++i) {
    int grow = m0 + wm + i * 16 + kq * 4;
#pragma unroll
    for (int j = 0; j < 4; ++j) {
      int gcol = n0 + wn + j * 16 + lm;
#pragma unroll
      for (int r = 0; r < 4; ++r) {
        int row = grow + r;
        float v = acc[i][j][r];
        if (g.mode == 0) {
          if (row < g.M && gcol < g.N) g.C[z][(size_t)row * g.ldc + gcol] = v;
        } else if (g.mode == 1) {
          float vv = v;
          if (row < g.M && gcol < g.N)
            vv += g.e1[(size_t)row * M2_ + gcol] + g.e2[(size_t)(row & 31) * M2_ + gcol];
          float other = __shfl_xor(vv, 1);
          if ((lane & 1) == 0 && row < g.M && gcol < g.N)
            g.tmax[(size_t)row * KW_ + (gcol >> 1)] = f2bf(fmaxf(vv, other));
        } else {
          if (row < g.M && gcol < g.N) {
            int t = row >> 5, b = row & 31;
            g.C[z][((size_t)b * T_ + t) * (size_t)g.ldc + gcol] = v;
          }
        }
      }
    }
  }
}

// ---------------------------------------------------------------------------
// Zero-RMW grid barrier. Arrival: each block stores phase to its OWN slot.
// Block 0's 256 threads poll all slots in parallel (coherent loads +
// __syncthreads_and), then set a broadcast flag. No atomic RMWs, no fences:
// all cross-block data moves via sc0/sc1 coherent ops, L2 never holds it.
// ---------------------------------------------------------------------------
__device__ __forceinline__ void gbar2(uint* slots, uint* flag, int nb,
                                      uint& phase, int bid, int tid) {
  asm volatile("s_waitcnt vmcnt(0)" ::: "memory");  // drain this wave's WT data stores
  __syncthreads();
  ++phase;
  if (tid == 0)
    __hip_atomic_store(&slots[bid], phase, __ATOMIC_RELAXED, __HIP_MEMORY_SCOPE_AGENT);
  if (bid == 0) {
    int done = 0;
    do {
      uint v = (tid < nb) ? __hip_atomic_load(&slots[tid], __ATOMIC_RELAXED,
                                              __HIP_MEMORY_SCOPE_AGENT)
                          : phase;
      done = __syncthreads_and((int)(v >= phase));
      if (!done) __builtin_amdgcn_s_sleep(1);
    } while (!done);
    if (tid == 0)
      __hip_atomic_store(flag, phase, __ATOMIC_RELAXED, __HIP_MEMORY_SCOPE_AGENT);
  } else {
    if (tid == 0) {
      while (__hip_atomic_load(flag, __ATOMIC_RELAXED, __HIP_MEMORY_SCOPE_AGENT) < phase)
        __builtin_amdgcn_s_sleep(1);
    }
    __syncthreads();
  }
}

// ---------------------------------------------------------------------------
// Persistent GRU sequence kernel. ONE launch per recurrence.
// Wave w owns batch rows b = w*8 .. w*8+7; lane l covers k = q*256 + 4l.
// h/rh reads are wave-contiguous (1 KB per instruction) coherent loads,
// 4-deep pipelined. Reduction = reduce-scatter shuffle tree that lands each
// (gate,row,col) sum on its designated lane (no LDS round trip).
// ---------------------------------------------------------------------------
struct Seq {
  int steps;
  const float* Xr; const float* Xz; const float* Xc;  // [steps][32][1000]
  const ushort *Ur, *Uz, *U;                          // bf16 [1000][1024]
  const float *cr, *cz, *cc;                          // nullable ctx adds
  const float *br, *bz, *bb;
  float* h;          // state [32][1024] fp32 (padding stays 0)
  float* rh;         // r*h scratch [32][1024]
  ushort* srm;       // if non-null: bf16 state log at (t+1)*32*1024
  uint* slots;       // [nb]
  uint* flag;
};

#define CAR(hv, r)                                                        \
  {                                                                       \
    float hx[4] = {hv[0], hv[1], hv[2], hv[3]};                           \
    _Pragma("unroll") for (int j_ = 0; j_ < 4; ++j_)                      \
        _Pragma("unroll") for (int e_ = 0; e_ < 4; ++e_) {                \
      accr[r][j_] = fmaf(hx[e_], wr[j_][e_], accr[r][j_]);                \
      accz[r][j_] = fmaf(hx[e_], wz[j_][e_], accz[r][j_]);                \
    }                                                                     \
  }
#define CAQ(p, q)                                                         \
  {                                                                       \
    float wr[4][4], wz[4][4];                                             \
    _Pragma("unroll") for (int j_ = 0; j_ < 4; ++j_) {                    \
      ushort4 u_ = *(const ushort4*)&Wlds[j_ * 1024 + (q) * 256 + lane4]; \
      ushort4 v_ = *(const ushort4*)&Wlds[4096 + j_ * 1024 + (q) * 256 + lane4]; \
      wr[j_][0] = bf2f(u_.x); wr[j_][1] = bf2f(u_.y);                     \
      wr[j_][2] = bf2f(u_.z); wr[j_][3] = bf2f(u_.w);                     \
      wz[j_][0] = bf2f(v_.x); wz[j_][1] = bf2f(v_.y);                     \
      wz[j_][2] = bf2f(v_.z); wz[j_][3] = bf2f(v_.w);                     \
    }                                                                     \
    CAR(p##0, 0) CAR(p##1, 1) CAR(p##2, 2) CAR(p##3, 3)                   \
    CAR(p##4, 4) CAR(p##5, 5) CAR(p##6, 6) CAR(p##7, 7)                   \
  }
#define CBR(hv, r)                                                        \
  {                                                                       \
    float hx[4] = {hv[0], hv[1], hv[2], hv[3]};                           \
    _Pragma("unroll") for (int j_ = 0; j_ < 4; ++j_)                      \
        _Pragma("unroll") for (int e_ = 0; e_ < 4; ++e_)                  \
      acc[r][j_] = fmaf(hx[e_], wu[j_][e_], acc[r][j_]);                  \
  }
#define CBQ(p, q)                                                         \
  {                                                                       \
    float wu[4][4];                                                       \
    _Pragma("unroll") for (int j_ = 0; j_ < 4; ++j_) {                    \
      ushort4 u_ = *(const ushort4*)&Wlds[8192 + j_ * 1024 + (q) * 256 + lane4]; \
      wu[j_][0] = bf2f(u_.x); wu[j_][1] = bf2f(u_.y);                     \
      wu[j_][2] = bf2f(u_.z); wu[j_][3] = bf2f(u_.w);                     \
    }                                                                     \
    CBR(p##0, 0) CBR(p##1, 1) CBR(p##2, 2) CBR(p##3, 3)                   \
    CBR(p##4, 4) CBR(p##5, 5) CBR(p##6, 6) CBR(p##7, 7)                   \
  }

__global__ __launch_bounds__(256, 1) void gru_seq(Seq a) {
  __shared__ ushort Wlds[3 * 4 * 1024];   // [mat][row 0..3][k 0..1023]
  __shared__ float  Xlds[24 * 384];       // [t][mat][b*4+j]
  __shared__ float  Clds[3][128];         // ctx adds [mat][b*4+j]
  __shared__ float  blds[3][4];           // biases   [mat][j]
  __shared__ float  zlds[128];            // z gate (block-local)
  __shared__ float  rhstage[128];
  __shared__ float  hstage[128];
  __shared__ ushort sstage[128];

  const int tid = threadIdx.x;
  const int bid = blockIdx.x;
  const int w = tid >> 6, lane = tid & 63;
  const int lane4 = lane * 4;
  const int j0 = bid * 4;
  const int nb = gridDim.x;
  uint phase = 0;

  // ---- one-time preload: weights -> LDS (bf16) ----
  {
    const ushort* Ws[3] = {a.Ur, a.Uz, a.U};
    for (int q = tid; q < 3 * 4 * 128; q += 256) {
      int mat = q >> 9;
      int rem = q & 511;
      int row = rem >> 7;
      int k8 = (rem & 127) << 3;
      *(bf16x8*)&Wlds[mat * 4096 + row * 1024 + k8] =
          *(const bf16x8*)(Ws[mat] + (size_t)(j0 + row) * HP_ + k8);
    }
  }
  // ---- one-time preload: X projections, all steps ----
  for (int q = tid; q < a.steps * 384; q += 256) {
    int t = q / 384;
    int rem = q - t * 384;
    int mat = rem >> 7;
    int r2 = rem & 127;
    const float* Xs = (mat == 0 ? a.Xr : mat == 1 ? a.Xz : a.Xc) + t * 32000;
    Xlds[q] = Xs[(r2 >> 2) * H_ + j0 + (r2 & 3)];
  }
  // ---- one-time preload: ctx adds + biases ----
  if (a.cr) {
    const float* Cs[3] = {a.cr, a.cz, a.cc};
    for (int q = tid; q < 3 * 128; q += 256) {
      int mat = q >> 7, r2 = q & 127;
      Clds[mat][r2] = Cs[mat][(r2 >> 2) * H_ + j0 + (r2 & 3)];
    }
  } else {
    for (int q = tid; q < 3 * 128; q += 256) Clds[q >> 7][q & 127] = 0.f;
  }
  if (tid < 12) {
    const float* bs[3] = {a.br, a.bz, a.bb};
    blds[tid >> 2][tid & 3] = bs[tid >> 2][j0 + (tid & 3)];
  }
  __syncthreads();

  for (int t = 0; t < a.steps; ++t) {
    // ================= phase A: pre_r, pre_z -> rh, z =================
    {
      float accr[8][4], accz[8][4];
#pragma unroll
      for (int r = 0; r < 8; ++r)
#pragma unroll
        for (int j = 0; j < 4; ++j) { accr[r][j] = 0.f; accz[r][j] = 0.f; }

      const float* hq = a.h + (size_t)(w * 8) * HP_ + lane4;
      DECLC(pa) DECLC(pb) DECLC(pc) DECLC(pd)
      LOADCQ(pa, hq) LOADCQ(pb, hq + 256) LOADCQ(pc, hq + 512)
      VWAIT(16)
      LOADCQ(pd, hq + 768)
      CAQ(pa, 0)
      VWAIT(16)
      CAQ(pb, 1)
      VWAIT(8)
      CAQ(pc, 2)
      VWAIT(0)
      CAQ(pd, 3)

      // reduce-scatter: lane l ends with sum for (g=l5, r=l4l3l2, j=l1l0)
      float s32[8][4];
#pragma unroll
      for (int x = 0; x < 8; ++x)
#pragma unroll
        for (int j = 0; j < 4; ++j) {
          float sd = (lane & 32) ? accr[x][j] : accz[x][j];
          float rv = __shfl_xor(sd, 32);
          float kp = (lane & 32) ? accz[x][j] : accr[x][j];
          s32[x][j] = kp + rv;
        }
      float s16[4][4];
#pragma unroll
      for (int x = 0; x < 4; ++x)
#pragma unroll
        for (int j = 0; j < 4; ++j) {
          float sd = (lane & 16) ? s32[x][j] : s32[x + 4][j];
          float rv = __shfl_xor(sd, 16);
          float kp = (lane & 16) ? s32[x + 4][j] : s32[x][j];
          s16[x][j] = kp + rv;
        }
      float s8[2][4];
#pragma unroll
      for (int x = 0; x < 2; ++x)
#pragma unroll
        for (int j = 0; j < 4; ++j) {
          float sd = (lane & 8) ? s16[x][j] : s16[x + 2][j];
          float rv = __shfl_xor(sd, 8);
          float kp = (lane & 8) ? s16[x + 2][j] : s16[x][j];
          s8[x][j] = kp + rv;
        }
      float s4v[4];
#pragma unroll
      for (int j = 0; j < 4; ++j) {
        float sd = (lane & 4) ? s8[0][j] : s8[1][j];
        float rv = __shfl_xor(sd, 4);
        float kp = (lane & 4) ? s8[1][j] : s8[0][j];
        s4v[j] = kp + rv;
      }
      float s2v[2];
#pragma unroll
      for (int y = 0; y < 2; ++y) {
        float sd = (lane & 2) ? s4v[y] : s4v[y + 2];
        float rv = __shfl_xor(sd, 2);
        float kp = (lane & 2) ? s4v[y + 2] : s4v[y];
        s2v[y] = kp + rv;
      }
      float sfin;
      {
        float sd = (lane & 1) ? s2v[0] : s2v[1];
        float rv = __shfl_xor(sd, 1);
        float kp = (lane & 1) ? s2v[1] : s2v[0];
        sfin = kp + rv;
      }

      {
        int g = lane >> 5, rr = (lane >> 2) & 7, jj = lane & 3;
        int bb = w * 8 + rr;
        int ex = bb * 4 + jj;
        float pre = sfin + Xlds[t * 384 + g * 128 + ex] + blds[g][jj] + Clds[g][ex];
        float sg = 1.f / (1.f + expf(-pre));
        if (g == 0) {
          float hval = ld_cv(a.h + (size_t)bb * HP_ + j0 + jj);
          rhstage[ex] = sg * hval;
        } else {
          zlds[ex] = sg;
        }
      }
      __syncthreads();
      if (tid < 32)
        st_wt4(a.rh + (size_t)tid * HP_ + j0, *(f32x4*)&rhstage[tid * 4]);
    }
    gbar2(a.slots, a.flag, nb, phase, bid, tid);

    // ================= phase B: cand -> h update =================
    {
      float acc[8][4];
#pragma unroll
      for (int r = 0; r < 8; ++r)
#pragma unroll
        for (int j = 0; j < 4; ++j) acc[r][j] = 0.f;

      const float* rq = a.rh + (size_t)(w * 8) * HP_ + lane4;
      DECLC(qa) DECLC(qb) DECLC(qc) DECLC(qd)
      LOADCQ(qa, rq) LOADCQ(qb, rq + 256) LOADCQ(qc, rq + 512)
      VWAIT(16)
      LOADCQ(qd, rq + 768)
      CBQ(qa, 0)
      VWAIT(16)
      CBQ(qb, 1)
      VWAIT(8)
      CBQ(qc, 2)
      VWAIT(0)
      CBQ(qd, 3)

      // reduce-scatter: lane l -> (r=l5l4l3, j=l2l1); lanes paired on bit0
      float t4[4][4];
#pragma unroll
      for (int x = 0; x < 4; ++x)
#pragma unroll
        for (int j = 0; j < 4; ++j) {
          float sd = (lane & 32) ? acc[x][j] : acc[x + 4][j];
          float rv = __shfl_xor(sd, 32);
          float kp = (lane & 32) ? acc[x + 4][j] : acc[x][j];
          t4[x][j] = kp + rv;
        }
      float t2[2][4];
#pragma unroll
      for (int x = 0; x < 2; ++x)
#pragma unroll
        for (int j = 0; j < 4; ++j) {
          float sd = (lane & 16) ? t4[x][j] : t4[x + 2][j];
          float rv = __shfl_xor(sd, 16);
          float kp = (lane & 16) ? t4[x + 2][j] : t4[x][j];
          t2[x][j] = kp + rv;
        }
      float t1[4];
#pragma unroll
      for (int j = 0; j < 4; ++j) {
        float sd = (lane & 8) ? t2[0][j] : t2[1][j];
        float rv = __shfl_xor(sd, 8);
        float kp = (lane & 8) ? t2[1][j] : t2[0][j];
        t1[j] = kp + rv;
      }
      float u1[2];
#pragma unroll
      for (int y = 0; y < 2; ++y) {
        float sd = (lane & 4) ? t1[y] : t1[y + 2];
        float rv = __shfl_xor(sd, 4);
        float kp = (lane & 4) ? t1[y + 2] : t1[y];
        u1[y] = kp + rv;
      }
      float v1;
      {
        float sd = (lane & 2) ? u1[0] : u1[1];
        float rv = __shfl_xor(sd, 2);
        float kp = (lane & 2) ? u1[1] : u1[0];
        v1 = kp + rv;
      }
      float sfin = v1 + __shfl_xor(v1, 1);

      {
        int rr = (lane >> 3) & 7, jj = (lane >> 1) & 3;
        int bb = w * 8 + rr;
        int ex = bb * 4 + jj;
        if (!(lane & 1)) {
          float cand = tanhf(sfin + Xlds[t * 384 + 256 + ex] + blds[2][jj] + Clds[2][ex]);
          float z = zlds[ex];
          float hold = ld_cv(a.h + (size_t)bb * HP_ + j0 + jj);
          float nv = (1.f - z) * hold + z * cand;
          hstage[ex] = nv;
          sstage[ex] = f2bf(nv);
        }
      }
      __syncthreads();
      if (tid < 32) {
        st_wt4(a.h + (size_t)tid * HP_ + j0, *(f32x4*)&hstage[tid * 4]);
        if (a.srm)
          *(ushort4*)(a.srm + (size_t)(t + 1) * B_ * HP_ + (size_t)tid * HP_ + j0) =
              *(ushort4*)&sstage[tid * 4];
      }
    }
    if (t != a.steps - 1) gbar2(a.slots, a.flag, nb, phase, bid, tid);
  }
}

// ---------------------------------------------------------------------------
// context projections + s0 (bf16 weights)
// ---------------------------------------------------------------------------
struct Ctx16 {
  const ushort* W[5];
  float* out[5];
  int mode[5];
  const float* x;
  float* hbk2;
  ushort* srm0;
};

__global__ __launch_bounds__(256) void ctx_mv16(Ctx16 a) {
  __shared__ float red[4][4][32];
  const int z = blockIdx.z;
  const ushort* __restrict__ W = a.W[z];
  const float* __restrict__ x = a.x;
  const int tid = threadIdx.x;
  const int w = tid >> 6, lane = tid & 63;
  const int b = lane & 31, kh = lane >> 5;
  const int j0 = blockIdx.x * 4;
  const int kbase = w * 256 + kh * 128;
  const float4* h4 = (const float4*)(x + b * HP_ + kbase);
  float acc[4] = {0.f, 0.f, 0.f, 0.f};
#pragma unroll
  for (int i = 0; i < 16; ++i) {
    float4 ha = h4[2 * i], hb = h4[2 * i + 1];
    float hv[8] = {ha.x, ha.y, ha.z, ha.w, hb.x, hb.y, hb.z, hb.w};
    int k = kbase + i * 8;
#pragma unroll
    for (int j = 0; j < 4; ++j) {
      bf16x8 u = *(const bf16x8*)(W + (size_t)(j0 + j) * HP_ + k);
#pragma unroll
      for (int e = 0; e < 8; ++e)
        acc[j] = fmaf(hv[e], bf2f((ushort)u[e]), acc[j]);
    }
  }
  float p[4];
#pragma unroll
  for (int j = 0; j < 4; ++j) p[j] = acc[j] + __shfl_xor(acc[j], 32);
  if (lane < 32) {
#pragma unroll
    for (int j = 0; j < 4; ++j) red[w][j][b] = p[j];
  }
  __syncthreads();
  if (tid < 128) {
    int eb = tid & 31, ej = tid >> 5;
    float s = red[0][ej][eb] + red[1][ej][eb] + red[2][ej][eb] + red[3][ej][eb];
    int j = j0 + ej;
    if (a.mode[z] == 0) {
      a.out[z][eb * H_ + j] = s;
    } else {
      float v = tanhf(s);
      a.hbk2[eb * HP_ + j] = v;
      a.srm0[eb * HP_ + j] = f2bf(v);
    }
  }
}

// ---------------------------------------------------------------------------
// Host
// ---------------------------------------------------------------------------
extern "C" void kernel_launch(void* const* d_in, const int* in_sizes, int n_in,
                              void* d_out, int out_size, void* d_ws, size_t ws_size,
                              hipStream_t stream) {
  const int*   src     = (const int*)d_in[0];
  const int*   tgt     = (const int*)d_in[1];
  const float* src_emb = (const float*)d_in[3];
  const float* tgt_emb = (const float*)d_in[4];
  const float* enc_W   = (const float*)d_in[5];
  const float* enc_Wz  = (const float*)d_in[6];
  const float* enc_Wr  = (const float*)d_in[7];
  const float* enc_U   = (const float*)d_in[8];
  const float* enc_Uz  = (const float*)d_in[9];
  const float* enc_Ur  = (const float*)d_in[10];
  const float* enc_b   = (const float*)d_in[11];
  const float* enc_bz  = (const float*)d_in[12];
  const float* enc_br  = (const float*)d_in[13];
  const float* dec_W   = (const float*)d_in[14];
  const float* dec_Wz  = (const float*)d_in[15];
  const float* dec_Wr  = (const float*)d_in[16];
  const float* dec_U   = (const float*)d_in[17];
  const float* dec_Uz  = (const float*)d_in[18];
  const float* dec_Ur  = (const float*)d_in[19];
  const float* dec_C   = (const float*)d_in[20];
  const float* dec_Cz  = (const float*)d_in[21];
  const float* dec_Cr  = (const float*)d_in[22];
  const float* dec_b   = (const float*)d_in[23];
  const float* dec_bz  = (const float*)d_in[24];
  const float* dec_br  = (const float*)d_in[25];
  const float* W_s     = (const float*)d_in[26];
  const float* U_o     = (const float*)d_in[27];
  const float* V_o     = (const float*)d_in[28];
  const float* C_o     = (const float*)d_in[29];
  const float* W_o     = (const float*)d_in[30];
  float* out = (float*)d_out;
  char* wsb = (char*)d_ws;
  (void)in_sizes; (void)n_in; (void)out_size; (void)ws_size;

  float*  hbk   = (float*)(wsb + 0);         // 32x1024
  float*  rhbk  = (float*)(wsb + 131072);
  float*  hbk2  = (float*)(wsb + 262144);
  ushort* Srm16 = (ushort*)(wsb + 393216);   // 768x1024 bf16
  ushort* Tmax  = (ushort*)(wsb + 1966080);  // 768x512 bf16
  float*  cCr   = (float*)(wsb + 2880512);
  float*  cCz   = (float*)(wsb + 3008512);
  float*  cC    = (float*)(wsb + 3136512);
  float*  cCo   = (float*)(wsb + 3264512);
  float*  YV    = (float*)(wsb + 3392512);   // 768x1000
  float*  XPr   = (float*)(wsb + 6464512);
  float*  XPz   = (float*)(wsb + 9536512);
  float*  XPc   = (float*)(wsb + 12608512);
  float*  YPr   = (float*)(wsb + 15680512);
  float*  YPz   = (float*)(wsb + 18752512);
  float*  YPc   = (float*)(wsb + 21824512);
  ushort* XE16  = (ushort*)(wsb + 24896512); // 768x640 bf16
  ushort* YE16  = (ushort*)(wsb + 25879552);
  ushort* H16   = (ushort*)(wsb + 26862592); // 12 x 1000x1024 bf16
  ushort* E16   = (ushort*)(wsb + 51438592); // 7 x 1000x640 bf16
  ushort* Wo16  = (ushort*)(wsb + 60398592); // 30000x512 bf16

  // barrier regions in first 8KB of out (overwritten by the logits GEMM)
  uint* slotsE = (uint*)((char*)d_out + 0);
  uint* flagE  = (uint*)((char*)d_out + 2048);
  uint* slotsD = (uint*)((char*)d_out + 4096);
  uint* flagD  = (uint*)((char*)d_out + 6144);

  hipMemsetAsync(wsb, 0, 2752512, stream);
  hipMemsetAsync(d_out, 0, 8192, stream);

  {
    ConvJobs a = {};
    const float* hin[12] = {enc_Ur, enc_Uz, enc_U, dec_Ur, dec_Uz, dec_U,
                            dec_Cr, dec_Cz, dec_C, C_o, W_s, U_o};
    const float* ein[7]  = {enc_Wr, enc_Wz, enc_W, dec_Wr, dec_Wz, dec_W, V_o};
    for (int i = 0; i < 12; ++i) {
      a.in[i] = hin[i]; a.out[i] = H16 + (size_t)i * 1000 * HP_;
      a.K[i] = H_; a.Kp[i] = HP_;
    }
    for (int i = 0; i < 7; ++i) {
      a.in[12 + i] = ein[i]; a.out[12 + i] = E16 + (size_t)i * 1000 * EP_;
      a.K[12 + i] = E_; a.Kp[12 + i] = EP_;
    }
    conv_small<<<dim3(1000, 19), dim3(256), 0, stream>>>(a);
  }
  conv_wo<<<dim3(V_), dim3(256), 0, stream>>>(W_o, Wo16);

  gather16<<<dim3(2 * S_ * B_), dim3(256), 0, stream>>>(src, tgt, src_emb, tgt_emb, XE16, YE16);

  {
    MG g = {};
    const ushort* As[7] = {XE16, XE16, XE16, YE16, YE16, YE16, YE16};
    float* Cs[7] = {XPr, XPz, XPc, YPr, YPz, YPc, YV};
    for (int i = 0; i < 7; ++i) {
      g.A[i] = As[i]; g.Bw[i] = E16 + (size_t)i * 1000 * EP_; g.C[i] = Cs[i];
    }
    g.M = S_ * B_; g.N = H_; g.Kp = EP_; g.ldc = H_; g.mode = 0;
    mgemm<<<dim3(8, 6, 7), dim3(256), 0, stream>>>(g);
  }

  const ushort* encUr16 = H16 + 0 * 1024000;
  const ushort* encUz16 = H16 + 1 * 1024000;
  const ushort* encU16  = H16 + 2 * 1024000;
  const ushort* decUr16 = H16 + 3 * 1024000;
  const ushort* decUz16 = H16 + 4 * 1024000;
  const ushort* decU16  = H16 + 5 * 1024000;
  const ushort* Uo16    = H16 + 11 * 1024000;

  {
    Seq a = {};
    a.steps = S_;
    a.Xr = XPr; a.Xz = XPz; a.Xc = XPc;
    a.Ur = encUr16; a.Uz = encUz16; a.U = encU16;
    a.cr = nullptr; a.cz = nullptr; a.cc = nullptr;
    a.br = enc_br; a.bz = enc_bz; a.bb = enc_b;
    a.h = hbk; a.rh = rhbk;
    a.srm = nullptr; a.slots = slotsE; a.flag = flagE;
    gru_seq<<<dim3(250), dim3(256), 0, stream>>>(a);
  }

  {
    Ctx16 a = {};
    for (int i = 0; i < 5; ++i) {
      a.W[i] = H16 + (size_t)(6 + i) * 1024000;
      a.mode[i] = (i == 4) ? 2 : 0;
    }
    a.out[0] = cCr; a.out[1] = cCz; a.out[2] = cC; a.out[3] = cCo; a.out[4] = nullptr;
    a.x = hbk; a.hbk2 = hbk2; a.srm0 = Srm16;
    ctx_mv16<<<dim3(250, 1, 5), dim3(256), 0, stream>>>(a);
  }

  {
    Seq a = {};
    a.steps = T_ - 1;
    a.Xr = YPr; a.Xz = YPz; a.Xc = YPc;
    a.Ur = decUr16; a.Uz = decUz16; a.U = decU16;
    a.cr = cCr; a.cz = cCz; a.cc = cC;
    a.br = dec_br; a.bz = dec_bz; a.bb = dec_b;
    a.h = hbk2; a.rh = rhbk;
    a.srm = Srm16; a.slots = slotsD; a.flag = flagD;
    gru_seq<<<dim3(250), dim3(256), 0, stream>>>(a);
  }

  {
    MG g = {};
    g.A[0] = Srm16; g.Bw[0] = Uo16;
    g.M = T_ * B_; g.N = M2_; g.Kp = HP_; g.ldc = 0; g.mode = 1;
    g.e1 = YV; g.e2 = cCo; g.tmax = Tmax;
    mgemm<<<dim3(8, 6, 1), dim3(256), 0, stream>>>(g);
  }

  {
    MG g = {};
    g.A[0] = Tmax; g.Bw[0] = Wo16; g.C[0] = out;
    g.M = T_ * B_; g.N = V_; g.Kp = KW_; g.ldc = V_; g.mode = 2;
    mgemm<<<dim3(235, 6, 1), dim3(256), 0, stream>>>(g);
  }
}